// Round 1
// baseline (325.311 us; speedup 1.0000x reference)
//
#include <hip/hip_runtime.h>
#include <math.h>

#define TPB 256

// ---------------- workspace layout (float offsets) ----------------
constexpr unsigned OFF_P    = 0u;                     // p    [4096][256]
constexpr unsigned OFF_K    = OFF_P    + 4096u*256u;  // k    [4096][64]
constexpr unsigned OFF_PA   = OFF_K    + 4096u*64u;   // pa   [4096][64]
constexpr unsigned OFF_R    = OFF_PA   + 4096u*64u;   // r    [512][64]
constexpr unsigned OFF_RA   = OFF_R    + 512u*64u;    // ra   [512][64]
constexpr unsigned OFF_SRP  = OFF_RA   + 512u*64u;    // Sr partials [8][512][64]
constexpr unsigned OFF_PMAX = OFF_SRP  + 8u*512u*64u; // pmax partials [256][64]
constexpr unsigned OFF_W1T  = OFF_PMAX + 256u*64u;    // W1^T [256][64]
constexpr unsigned OFF_W2T  = OFF_W1T  + 256u*64u;    // W2^T [256][64]

// ============================================================================
// K1: p = relu(protein @ Wc^T + bc)   [4096,1024]x[1024,256] -> ws[OFF_P]
//     + 2 tail blocks transpose W1, W2 into ws for coalesced reads in K2.
// BM=32, BN=64, BK=16; 512 GEMM blocks (2 blocks/CU -> 2 waves/SIMD).
// ============================================================================
__global__ __launch_bounds__(TPB) void k1_gemm(
    const float* __restrict__ prot, const float* __restrict__ Wc,
    const float* __restrict__ bc,   const float* __restrict__ W1,
    const float* __restrict__ W2,   float* __restrict__ ws)
{
  int bid = blockIdx.x;
  int tid = threadIdx.x;
  if (bid >= 512) {
    // transpose W[64][256] -> WT[256][64]
    const float* W = (bid == 512) ? W1 : W2;
    float* WT = ws + ((bid == 512) ? OFF_W1T : OFF_W2T);
    for (int it = 0; it < 64; ++it) {
      int idx = it * TPB + tid;          // 16384 elems
      int j = idx >> 8, cc = idx & 255;
      WT[cc * 64 + j] = W[idx];
    }
    return;
  }
  __shared__ float As[16 * 36];   // [kk][m], padded
  __shared__ float Bs[16 * 68];   // [kk][n], padded
  int m0 = (bid >> 2) * 32;
  int n0 = (bid & 3) * 64;
  int tm = tid & 15, tn = tid >> 4;          // micro: 2 rows x 4 cols
  int lmA = tid >> 3, k2 = (tid & 7) * 2;    // A staging: 32 rows x 8 float2
  int lmB = tid >> 2, k4 = (tid & 3) * 4;    // B staging: 64 rows x 4 float4
  const float* Ap = prot + (m0 + lmA) * 1024 + k2;
  const float* Bp = Wc   + (n0 + lmB) * 1024 + k4;
  float acc[2][4] = {};
  for (int kt = 0; kt < 1024; kt += 16) {
    float2 av = *(const float2*)(Ap + kt);
    float4 bv = *(const float4*)(Bp + kt);
    As[(k2 + 0) * 36 + lmA] = av.x;
    As[(k2 + 1) * 36 + lmA] = av.y;
    Bs[(k4 + 0) * 68 + lmB] = bv.x;
    Bs[(k4 + 1) * 68 + lmB] = bv.y;
    Bs[(k4 + 2) * 68 + lmB] = bv.z;
    Bs[(k4 + 3) * 68 + lmB] = bv.w;
    __syncthreads();
#pragma unroll
    for (int kk = 0; kk < 16; ++kk) {
      float2 a = *(const float2*)&As[kk * 36 + tm * 2];
      float4 b = *(const float4*)&Bs[kk * 68 + tn * 4];
      acc[0][0] += a.x * b.x; acc[0][1] += a.x * b.y;
      acc[0][2] += a.x * b.z; acc[0][3] += a.x * b.w;
      acc[1][0] += a.y * b.x; acc[1][1] += a.y * b.y;
      acc[1][2] += a.y * b.z; acc[1][3] += a.y * b.w;
    }
    __syncthreads();
  }
  float4 bias = *(const float4*)&bc[n0 + tn * 4];
#pragma unroll
  for (int i = 0; i < 2; ++i) {
    float4 o;
    o.x = fmaxf(acc[i][0] + bias.x, 0.f);
    o.y = fmaxf(acc[i][1] + bias.y, 0.f);
    o.z = fmaxf(acc[i][2] + bias.z, 0.f);
    o.w = fmaxf(acc[i][3] + bias.w, 0.f);
    *(float4*)&ws[OFF_P + (m0 + tm * 2 + i) * 256u + n0 + tn * 4] = o;
  }
}

// ============================================================================
// K2: two heads, unified code path (144 blocks, 32 rows each):
//   bid<128 : k  = relu(p @ W1^T + b1);  pa = k @ Wpa^T + bpa
//   bid>=128: r  = relu(react @ W2^T+b2); ra = r @ Wra^T + bra
// ============================================================================
__global__ __launch_bounds__(TPB) void k2_heads(
    const float* __restrict__ reactions,
    const float* __restrict__ b1,  const float* __restrict__ b2,
    const float* __restrict__ Wpa, const float* __restrict__ bpa,
    const float* __restrict__ Wra, const float* __restrict__ bra,
    float* __restrict__ ws)
{
  __shared__ float ps[32 * 256];   // src tile
  __shared__ float ks[32 * 65];    // first-stage output tile (padded)
  __shared__ float wst[64 * 65];   // 2nd-stage weight transposed (padded)
  int bid = blockIdx.x, tid = threadIdx.x;
  bool isProt = bid < 128;
  int row0 = (isProt ? bid : (bid - 128)) * 32;
  const float* src  = isProt ? (ws + OFF_P) : reactions;
  const float* WTg  = ws + (isProt ? OFF_W1T : OFF_W2T);
  const float* bv   = isProt ? b1 : b2;
  const float* W2nd = isProt ? Wpa : Wra;
  const float* b2nd = isProt ? bpa : bra;
  float* out1 = ws + (isProt ? OFF_K : OFF_R);
  float* out2 = ws + (isProt ? OFF_PA : OFF_RA);

  for (int it = 0; it < 8; ++it) {               // stage src [32][256]
    int i4 = it * TPB + tid;
    int row = i4 >> 6, c4 = (i4 & 63) * 4;
    *(float4*)&ps[row * 256 + c4] =
        *(const float4*)(src + (row0 + row) * 256u + c4);
  }
  for (int it = 0; it < 16; ++it) {              // wst[j][j2] = W2nd[j2][j]
    int idx = it * TPB + tid;
    int a = idx >> 6, b = idx & 63;
    wst[b * 65 + a] = W2nd[idx];
  }
  __syncthreads();

  int j = tid & 63, g = tid >> 6;                // j = out channel, g = row grp
  float acc[8];
  float bb = bv[j];
#pragma unroll
  for (int i = 0; i < 8; ++i) acc[i] = bb;
#pragma unroll 4
  for (int cc = 0; cc < 256; ++cc) {
    float w = WTg[cc * 64 + j];                  // coalesced global (L2)
#pragma unroll
    for (int i = 0; i < 8; ++i)
      acc[i] += ps[(g * 8 + i) * 256 + cc] * w;  // LDS broadcast
  }
#pragma unroll
  for (int i = 0; i < 8; ++i) {
    float kv = fmaxf(acc[i], 0.f);
    int row = g * 8 + i;
    out1[(row0 + row) * 64u + j] = kv;
    ks[row * 65 + j] = kv;
  }
  __syncthreads();

  float bb2 = b2nd[j];
  float acc2[8];
#pragma unroll
  for (int i = 0; i < 8; ++i) acc2[i] = bb2;
#pragma unroll 4
  for (int jj = 0; jj < 64; ++jj) {
    float w = wst[jj * 65 + j];
#pragma unroll
    for (int i = 0; i < 8; ++i)
      acc2[i] += ks[(g * 8 + i) * 65 + jj] * w;
  }
#pragma unroll
  for (int i = 0; i < 8; ++i)
    out2[(row0 + g * 8 + i) * 64u + j] = acc2[i];
}

// ============================================================================
// K3: interaction sums. 512 blocks:
//   bid<256 : Sr partials: block=(q-tile of 16, L-slice of 512)
//   bid>=256: Sp (full q sum) for l-tile of 16 + FUSED p_gate + k*(1+g) + max
// ============================================================================
__global__ __launch_bounds__(TPB) void k3_interact(
    const float* __restrict__ Wa, const float* __restrict__ ba,
    float* __restrict__ ws)
{
  // sm layout: [0,4096) tile; [4096,5120) sp; [5120,9280) WaT 64x65; [9280,9536) red
  __shared__ float sm[9536];
  int bid = blockIdx.x, tid = threadIdx.x;
  int c = tid & 63, g = tid >> 6;
  const float* ra = ws + OFF_RA;
  const float* pa = ws + OFF_PA;

  if (bid < 256) {
    int qt = bid >> 3, ls = bid & 7;
    int q0 = qt * 16, l0 = ls * 512;
    float u[4], acc[4];
#pragma unroll
    for (int i = 0; i < 4; ++i) {
      u[i] = ra[(q0 + g * 4 + i) * 64u + c];
      acc[i] = 0.f;
    }
    for (int chunk = 0; chunk < 8; ++chunk) {
      unsigned base = (unsigned)(l0 + chunk * 64) * 64u;
      for (int it = 0; it < 4; ++it) {
        int i4 = it * TPB + tid;
        int row = i4 >> 4, c4 = (i4 & 15) * 4;
        *(float4*)&sm[row * 64 + c4] = *(const float4*)(pa + base + row * 64 + c4);
      }
      __syncthreads();
#pragma unroll 4
      for (int ll = 0; ll < 64; ++ll) {
        float x = sm[ll * 64 + c];
#pragma unroll
        for (int i = 0; i < 4; ++i) acc[i] += fmaxf(u[i] + x, 0.f);
      }
      __syncthreads();
    }
#pragma unroll
    for (int i = 0; i < 4; ++i)
      ws[OFF_SRP + (unsigned)(ls * 512 + q0 + g * 4 + i) * 64u + c] = acc[i];
  } else {
    int b = bid - 256;
    int l0 = b * 16;
    for (int it = 0; it < 16; ++it) {            // WaT[j][c'] = Wa[c'][j]
      int idx = it * TPB + tid;
      int a = idx >> 6, bb = idx & 63;
      sm[5120 + bb * 65 + a] = Wa[idx];
    }
    float v[4], acc[4];
#pragma unroll
    for (int i = 0; i < 4; ++i) {
      v[i] = pa[(unsigned)(l0 + g * 4 + i) * 64u + c];
      acc[i] = 0.f;
    }
    for (int chunk = 0; chunk < 8; ++chunk) {
      unsigned base = (unsigned)(chunk * 64) * 64u;
      for (int it = 0; it < 4; ++it) {
        int i4 = it * TPB + tid;
        int row = i4 >> 4, c4 = (i4 & 15) * 4;
        *(float4*)&sm[row * 64 + c4] = *(const float4*)(ra + base + row * 64 + c4);
      }
      __syncthreads();
#pragma unroll 4
      for (int qq = 0; qq < 64; ++qq) {
        float x = sm[qq * 64 + c];
#pragma unroll
        for (int i = 0; i < 4; ++i) acc[i] += fmaxf(v[i] + x, 0.f);
      }
      __syncthreads();
    }
#pragma unroll
    for (int i = 0; i < 4; ++i) sm[4096 + (g * 4 + i) * 64 + c] = acc[i];
    __syncthreads();
    // fused p_gate + val + partial max over this block's 16 l-rows
    float vmax = 0.f;   // vals are >= 0 (k>=0, gate>0)
    float bac = ba[c];
#pragma unroll
    for (int i = 0; i < 4; ++i) {
      int ll = g * 4 + i;
      float dot = 0.f;
#pragma unroll 8
      for (int jj = 0; jj < 64; ++jj)
        dot += sm[4096 + ll * 64 + jj] * sm[5120 + jj * 65 + c];
      float pg = 1.f / (1.f + __expf(-(dot * (1.f / 512.f) + bac)));
      float val = ws[OFF_K + (unsigned)(l0 + ll) * 64u + c] * (1.f + pg);
      vmax = fmaxf(vmax, val);
    }
    sm[9280 + g * 64 + c] = vmax;
    __syncthreads();
    if (tid < 64) {
      float m = fmaxf(fmaxf(sm[9280 + tid], sm[9280 + 64 + tid]),
                      fmaxf(sm[9280 + 128 + tid], sm[9280 + 192 + tid]));
      ws[OFF_PMAX + (unsigned)b * 64u + tid] = m;
    }
  }
}

// ============================================================================
// K5: prot max-reduce, r_gate, ctx, 3-layer MLP. 16 blocks x 32 q-rows.
// LDS pool with phase aliasing (<= 64KB).
// ============================================================================
__global__ __launch_bounds__(TPB) void k5_final(
    const float* __restrict__ ba,
    const float* __restrict__ Wa,
    const float* __restrict__ Wf1, const float* __restrict__ bf1,
    const float* __restrict__ Wf2, const float* __restrict__ bf2,
    const float* __restrict__ Wf3, const float* __restrict__ bf3,
    const float* __restrict__ ws,  float* __restrict__ out)
{
  // S_CTX  [0,4224)      ctxT[128][33]   (later aliased by h2T[128][33])
  // S_H1   [4224,12672)  h1T[256][33]    (early: WaT 64x65 @4224, Mr 32x64 @8384)
  // S_PROT [12672,12736) ; S_RED [12736,12992)
  __shared__ float sm[12992];
  const int S_CTX = 0, S_H1 = 4224, S_WAT = 4224, S_MR = 8384;
  const int S_PROT = 12672, S_RED = 12736, S_H2 = 0;
  int bid = blockIdx.x, tid = threadIdx.x;
  int q0 = bid * 32;

  for (int it = 0; it < 16; ++it) {              // WaT[j][c'] = Wa[c'][j]
    int idx = it * TPB + tid;
    int a = idx >> 6, b = idx & 63;
    sm[S_WAT + b * 65 + a] = Wa[idx];
  }
  for (int it = 0; it < 8; ++it) {               // Mr tile = mean over L
    int idx = it * TPB + tid;                    // 2048 = 32q x 64c
    int q = idx >> 6, cc = idx & 63;
    float s = 0.f;
#pragma unroll
    for (int ls = 0; ls < 8; ++ls)
      s += ws[OFF_SRP + (unsigned)(ls * 512 + q0 + q) * 64u + cc];
    sm[S_MR + idx] = s * (1.f / 4096.f);
  }
  {                                              // prot partial max
    int cc = tid & 63, ch = tid >> 6;
    float m = 0.f;
    for (int i = ch; i < 256; i += 4)
      m = fmaxf(m, ws[OFF_PMAX + (unsigned)i * 64u + cc]);
    sm[S_RED + ch * 64 + cc] = m;
  }
  __syncthreads();
  if (tid < 64) {
    float m = fmaxf(fmaxf(sm[S_RED + tid], sm[S_RED + 64 + tid]),
                    fmaxf(sm[S_RED + 128 + tid], sm[S_RED + 192 + tid]));
    sm[S_PROT + tid] = m;
  }
  __syncthreads();
  {                                              // r_gate -> ctxT
    int cc = tid & 63, qg = tid >> 6;
    float bac = ba[cc];
    float pc = sm[S_PROT + cc];
#pragma unroll
    for (int i = 0; i < 8; ++i) {
      int q = qg * 8 + i;
      float dot = 0.f;
#pragma unroll 8
      for (int jj = 0; jj < 64; ++jj)
        dot += sm[S_MR + q * 64 + jj] * sm[S_WAT + jj * 65 + cc];
      float gg = 1.f / (1.f + __expf(-(dot + bac)));
      float rv = ws[OFF_R + (unsigned)(q0 + q) * 64u + cc];
      sm[S_CTX + cc * 33 + q] = rv * (1.f + gg);
      sm[S_CTX + (64 + cc) * 33 + q] = pc;
    }
  }
  __syncthreads();
  {                                              // h1 = leaky(ctx @ Wf1^T + bf1)
    int q = tid & 31, half = tid >> 5;
    for (int i = 0; i < 32; ++i) {
      int n = half * 32 + i;
      float acc = bf1[n];
      const float* wrow = Wf1 + n * 128;
#pragma unroll 8
      for (int j4 = 0; j4 < 32; ++j4) {
        float4 w = *(const float4*)(wrow + j4 * 4);
        acc += sm[S_CTX + (j4 * 4 + 0) * 33 + q] * w.x
             + sm[S_CTX + (j4 * 4 + 1) * 33 + q] * w.y
             + sm[S_CTX + (j4 * 4 + 2) * 33 + q] * w.z
             + sm[S_CTX + (j4 * 4 + 3) * 33 + q] * w.w;
      }
      acc = (acc > 0.f) ? acc : 0.01f * acc;
      sm[S_H1 + n * 33 + q] = acc;
    }
  }
  __syncthreads();
  {                                              // h2 = leaky(h1 @ Wf2^T + bf2)
    int q = tid & 31, half = tid >> 5;
    for (int i = 0; i < 16; ++i) {
      int mrow = half * 16 + i;
      float acc = bf2[mrow];
      const float* wrow = Wf2 + mrow * 256;
#pragma unroll 8
      for (int j4 = 0; j4 < 64; ++j4) {
        float4 w = *(const float4*)(wrow + j4 * 4);
        acc += sm[S_H1 + (j4 * 4 + 0) * 33 + q] * w.x
             + sm[S_H1 + (j4 * 4 + 1) * 33 + q] * w.y
             + sm[S_H1 + (j4 * 4 + 2) * 33 + q] * w.z
             + sm[S_H1 + (j4 * 4 + 3) * 33 + q] * w.w;
      }
      acc = (acc > 0.f) ? acc : 0.01f * acc;
      sm[S_H2 + mrow * 33 + q] = acc;
    }
  }
  __syncthreads();
  {                                              // out = h2 @ Wf3^T + bf3
    int q = tid & 31, part = tid >> 5;
    float acc = 0.f;
#pragma unroll
    for (int j = 0; j < 16; ++j) {
      int mrow = part * 16 + j;
      acc += sm[S_H2 + mrow * 33 + q] * Wf3[mrow];
    }
    sm[S_RED + part * 32 + q] = acc;
  }
  __syncthreads();
  if (tid < 32) {
    float s = bf3[0];
#pragma unroll
    for (int part = 0; part < 8; ++part) s += sm[S_RED + part * 32 + tid];
    out[q0 + tid] = s;
  }
}

// ============================================================================
extern "C" void kernel_launch(void* const* d_in, const int* in_sizes, int n_in,
                              void* d_out, int out_size, void* d_ws, size_t ws_size,
                              hipStream_t stream)
{
  const float* reactions = (const float*)d_in[0];
  const float* protein   = (const float*)d_in[1];
  const float* Wc  = (const float*)d_in[2];
  const float* bc  = (const float*)d_in[3];
  const float* W1  = (const float*)d_in[4];
  const float* b1  = (const float*)d_in[5];
  const float* W2  = (const float*)d_in[6];
  const float* b2  = (const float*)d_in[7];
  const float* Wa  = (const float*)d_in[8];
  const float* ba  = (const float*)d_in[9];
  const float* Wpa = (const float*)d_in[10];
  const float* bpa = (const float*)d_in[11];
  const float* Wra = (const float*)d_in[12];
  const float* bra = (const float*)d_in[13];
  const float* Wf1 = (const float*)d_in[14];
  const float* bf1 = (const float*)d_in[15];
  const float* Wf2 = (const float*)d_in[16];
  const float* bf2 = (const float*)d_in[17];
  const float* Wf3 = (const float*)d_in[18];
  const float* bf3 = (const float*)d_in[19];
  float* ws  = (float*)d_ws;
  float* out = (float*)d_out;

  hipLaunchKernelGGL(k1_gemm, dim3(514), dim3(TPB), 0, stream,
                     protein, Wc, bc, W1, W2, ws);
  hipLaunchKernelGGL(k2_heads, dim3(144), dim3(TPB), 0, stream,
                     reactions, b1, b2, Wpa, bpa, Wra, bra, ws);
  hipLaunchKernelGGL(k3_interact, dim3(512), dim3(TPB), 0, stream,
                     Wa, ba, ws);
  hipLaunchKernelGGL(k5_final, dim3(16), dim3(TPB), 0, stream,
                     ba, Wa, Wf1, bf1, Wf2, bf2, Wf3, bf3, ws, out);
}

// Round 2
// 231.271 us; speedup vs baseline: 1.4066x; 1.4066x over previous
//
#include <hip/hip_runtime.h>
#include <math.h>

#define TPB 256

// ---------------- workspace layout (float offsets) ----------------
constexpr unsigned OFF_P    = 0u;                     // p    [4096][256] (relu'd)
constexpr unsigned OFF_K    = OFF_P    + 4096u*256u;  // k    [4096][64]
constexpr unsigned OFF_PA   = OFF_K    + 4096u*64u;   // pa   [4096][64]
constexpr unsigned OFF_R    = OFF_PA   + 4096u*64u;   // r    [512][64]
constexpr unsigned OFF_RA   = OFF_R    + 512u*64u;    // ra   [512][64]
constexpr unsigned OFF_SRP  = OFF_RA   + 512u*64u;    // Sr partials [8][512][64]
constexpr unsigned OFF_PMAX = OFF_SRP  + 8u*512u*64u; // pmax partials [256][64]
constexpr unsigned OFF_W1T  = OFF_PMAX + 256u*64u;    // W1^T  [256][64]
constexpr unsigned OFF_W2T  = OFF_W1T  + 256u*64u;    // W2^T  [256][64]
constexpr unsigned OFF_WF1T = OFF_W2T  + 256u*64u;    // Wf1^T [128][256]
constexpr unsigned OFF_WF2T = OFF_WF1T + 128u*256u;   // Wf2^T [256][128]

// ============================================================================
// K1: p = relu(protein @ Wc^T + bc)  [4096,1024]x[1024,256]
// 256 blocks x 256 threads. Tile 64x64. Wave-private K-split: wave w owns
// K-chunk [w*256, w*256+256) with its OWN LDS staging tiles -> no barriers in
// the K-loop. 8x8 register micro-tile (64 FMA per 64B LDS read -> VALU-bound).
// Cross-wave LDS reduction + bias + relu epilogue.
// Tail blocks 256..261 transpose W1,W2,Wf1,Wf2 into ws.
// ============================================================================
__global__ __launch_bounds__(TPB, 1) void k1_gemm(
    const float* __restrict__ prot, const float* __restrict__ Wc,
    const float* __restrict__ bc,   const float* __restrict__ W1,
    const float* __restrict__ W2,   const float* __restrict__ Wf1,
    const float* __restrict__ Wf2,  float* __restrict__ ws)
{
  int bid = blockIdx.x;
  int tid = threadIdx.x;
  if (bid >= 256) {
    int tb = bid - 256;
    if (tb < 2) {                       // W1T/W2T [256][64]
      const float* W = (tb == 0) ? W1 : W2;
      float* WT = ws + ((tb == 0) ? OFF_W1T : OFF_W2T);
      for (int it = 0; it < 64; ++it) {
        int idx = it * TPB + tid;
        WT[idx] = W[(idx & 63) * 256 + (idx >> 6)];
      }
    } else if (tb < 4) {                // Wf1T [128][256], halves
      int h = tb - 2;
      for (int it = 0; it < 64; ++it) {
        int idx = h * 16384 + it * TPB + tid;
        ws[OFF_WF1T + idx] = Wf1[(idx & 255) * 128 + (idx >> 8)];
      }
    } else {                            // Wf2T [256][128], halves
      int h = tb - 4;
      for (int it = 0; it < 64; ++it) {
        int idx = h * 16384 + it * TPB + tid;
        ws[OFF_WF2T + idx] = Wf2[(idx & 127) * 256 + (idx >> 7)];
      }
    }
    return;
  }

  // phase1: per-wave As/Bs tiles (4 x 2304 floats = 36 KB)
  // phase2 (after barrier): reduction buffers 3 x 4096 floats = 48 KB
  __shared__ float sm[12288];
  int wave = tid >> 6, lane = tid & 63;
  float* As = sm + wave * 2304;         // [16 kk][72 pad] layout [kk][m]
  float* Bs = As + 1152;                // [16 kk][72 pad] layout [kk][n]

  int m0 = (bid >> 2) * 64;
  int n0 = (bid & 3) * 64;
  int kb0 = wave * 256;                 // this wave's K-chunk
  int r_ = lane >> 2, c4 = (lane & 3) * 4;   // staging: 16 rows x 4 float4
  int tn = lane & 7, tm = lane >> 3;         // micro-tile coords

  const float* Ag = prot + (m0 + r_) * 1024 + kb0 + c4;
  const float* Bg = Wc   + (n0 + r_) * 1024 + kb0 + c4;

  float4 ar[4], br[4];
#pragma unroll
  for (int p = 0; p < 4; ++p) {         // prefetch kt=0
    ar[p] = *(const float4*)(Ag + p * 16 * 1024);
    br[p] = *(const float4*)(Bg + p * 16 * 1024);
  }
  float acc[8][8] = {};

  for (int kt = 0; kt < 16; ++kt) {
#pragma unroll
    for (int p = 0; p < 4; ++p) {       // regs -> LDS (transposed [kk][m])
      int row = p * 16 + r_;
      As[(c4 + 0) * 72 + row] = ar[p].x;
      As[(c4 + 1) * 72 + row] = ar[p].y;
      As[(c4 + 2) * 72 + row] = ar[p].z;
      As[(c4 + 3) * 72 + row] = ar[p].w;
      Bs[(c4 + 0) * 72 + row] = br[p].x;
      Bs[(c4 + 1) * 72 + row] = br[p].y;
      Bs[(c4 + 2) * 72 + row] = br[p].z;
      Bs[(c4 + 3) * 72 + row] = br[p].w;
    }
    if (kt < 15) {                      // prefetch next kt during compute
#pragma unroll
      for (int p = 0; p < 4; ++p) {
        ar[p] = *(const float4*)(Ag + (kt + 1) * 16 + p * 16 * 1024);
        br[p] = *(const float4*)(Bg + (kt + 1) * 16 + p * 16 * 1024);
      }
    }
#pragma unroll
    for (int kk = 0; kk < 16; ++kk) {
      float4 a0 = *(const float4*)&As[kk * 72 + tm * 8];
      float4 a1 = *(const float4*)&As[kk * 72 + tm * 8 + 4];
      float4 b0 = *(const float4*)&Bs[kk * 72 + tn * 8];
      float4 b1 = *(const float4*)&Bs[kk * 72 + tn * 8 + 4];
      float av[8] = {a0.x, a0.y, a0.z, a0.w, a1.x, a1.y, a1.z, a1.w};
      float bv[8] = {b0.x, b0.y, b0.z, b0.w, b1.x, b1.y, b1.z, b1.w};
#pragma unroll
      for (int i = 0; i < 8; ++i)
#pragma unroll
        for (int j = 0; j < 8; ++j) acc[i][j] += av[i] * bv[j];
    }
  }

  __syncthreads();                      // all waves done with As/Bs
  if (wave > 0) {
    float* R = sm + (wave - 1) * 4096;
#pragma unroll
    for (int i = 0; i < 8; ++i) {
      *(float4*)&R[(tm * 8 + i) * 64 + tn * 8]     =
          make_float4(acc[i][0], acc[i][1], acc[i][2], acc[i][3]);
      *(float4*)&R[(tm * 8 + i) * 64 + tn * 8 + 4] =
          make_float4(acc[i][4], acc[i][5], acc[i][6], acc[i][7]);
    }
  }
  __syncthreads();
  if (wave == 0) {
#pragma unroll
    for (int i = 0; i < 8; ++i) {
      int row = m0 + tm * 8 + i;
#pragma unroll
      for (int j4 = 0; j4 < 2; ++j4) {
        float4 s = make_float4(acc[i][j4 * 4 + 0], acc[i][j4 * 4 + 1],
                               acc[i][j4 * 4 + 2], acc[i][j4 * 4 + 3]);
#pragma unroll
        for (int w = 0; w < 3; ++w) {
          float4 r = *(const float4*)&sm[w * 4096 + (tm * 8 + i) * 64 + tn * 8 + j4 * 4];
          s.x += r.x; s.y += r.y; s.z += r.z; s.w += r.w;
        }
        float4 bcv = *(const float4*)&bc[n0 + tn * 8 + j4 * 4];
        float4 o;
        o.x = fmaxf(s.x + bcv.x, 0.f);
        o.y = fmaxf(s.y + bcv.y, 0.f);
        o.z = fmaxf(s.z + bcv.z, 0.f);
        o.w = fmaxf(s.w + bcv.w, 0.f);
        *(float4*)&ws[OFF_P + (unsigned)row * 256u + n0 + tn * 8 + j4 * 4] = o;
      }
    }
  }
}

// ============================================================================
// K2: two heads, unified code path (144 blocks, 32 rows each):
//   bid<128 : k  = relu(p @ W1^T + b1);  pa = k @ Wpa^T + bpa
//   bid>=128: r  = relu(react @ W2^T+b2); ra = r @ Wra^T + bra
// ============================================================================
__global__ __launch_bounds__(TPB) void k2_heads(
    const float* __restrict__ reactions,
    const float* __restrict__ b1,  const float* __restrict__ b2,
    const float* __restrict__ Wpa, const float* __restrict__ bpa,
    const float* __restrict__ Wra, const float* __restrict__ bra,
    float* __restrict__ ws)
{
  __shared__ float ps[32 * 256];   // src tile
  __shared__ float ks[32 * 65];    // first-stage output tile (padded)
  __shared__ float wst[64 * 65];   // 2nd-stage weight transposed (padded)
  int bid = blockIdx.x, tid = threadIdx.x;
  bool isProt = bid < 128;
  int row0 = (isProt ? bid : (bid - 128)) * 32;
  const float* src  = isProt ? (ws + OFF_P) : reactions;
  const float* WTg  = ws + (isProt ? OFF_W1T : OFF_W2T);
  const float* bv   = isProt ? b1 : b2;
  const float* W2nd = isProt ? Wpa : Wra;
  const float* b2nd = isProt ? bpa : bra;
  float* out1 = ws + (isProt ? OFF_K : OFF_R);
  float* out2 = ws + (isProt ? OFF_PA : OFF_RA);

  for (int it = 0; it < 8; ++it) {               // stage src [32][256]
    int i4 = it * TPB + tid;
    int row = i4 >> 6, c4 = (i4 & 63) * 4;
    *(float4*)&ps[row * 256 + c4] =
        *(const float4*)(src + (row0 + row) * 256u + c4);
  }
  for (int it = 0; it < 16; ++it) {              // wst[j][j2] = W2nd[j2][j]
    int idx = it * TPB + tid;
    int a = idx >> 6, b = idx & 63;
    wst[b * 65 + a] = W2nd[idx];
  }
  __syncthreads();

  int j = tid & 63, g = tid >> 6;                // j = out channel, g = row grp
  float acc[8];
  float bb = bv[j];
#pragma unroll
  for (int i = 0; i < 8; ++i) acc[i] = bb;
#pragma unroll 4
  for (int cc = 0; cc < 256; ++cc) {
    float w = WTg[cc * 64 + j];                  // coalesced global (L2)
#pragma unroll
    for (int i = 0; i < 8; ++i)
      acc[i] += ps[(g * 8 + i) * 256 + cc] * w;  // LDS broadcast
  }
#pragma unroll
  for (int i = 0; i < 8; ++i) {
    float kv = fmaxf(acc[i], 0.f);
    int row = g * 8 + i;
    out1[(row0 + row) * 64u + j] = kv;
    ks[row * 65 + j] = kv;
  }
  __syncthreads();

  float bb2 = b2nd[j];
  float acc2[8];
#pragma unroll
  for (int i = 0; i < 8; ++i) acc2[i] = bb2;
#pragma unroll 4
  for (int jj = 0; jj < 64; ++jj) {
    float w = wst[jj * 65 + j];
#pragma unroll
    for (int i = 0; i < 8; ++i)
      acc2[i] += ks[(g * 8 + i) * 65 + jj] * w;
  }
#pragma unroll
  for (int i = 0; i < 8; ++i)
    out2[(row0 + g * 8 + i) * 64u + j] = acc2[i];
}

// ============================================================================
// K3: interaction sums. 512 blocks:
//   bid<256 : Sr partials: block=(q-tile of 16, L-slice of 512)
//   bid>=256: Sp (full q sum) for l-tile of 16 + FUSED p_gate + k*(1+g) + max
// ============================================================================
__global__ __launch_bounds__(TPB) void k3_interact(
    const float* __restrict__ Wa, const float* __restrict__ ba,
    float* __restrict__ ws)
{
  // sm layout: [0,4096) tile; [4096,5120) sp; [5120,9280) WaT 64x65; [9280,9536) red
  __shared__ float sm[9536];
  int bid = blockIdx.x, tid = threadIdx.x;
  int c = tid & 63, g = tid >> 6;
  const float* ra = ws + OFF_RA;
  const float* pa = ws + OFF_PA;

  if (bid < 256) {
    int qt = bid >> 3, ls = bid & 7;
    int q0 = qt * 16, l0 = ls * 512;
    float u[4], acc[4];
#pragma unroll
    for (int i = 0; i < 4; ++i) {
      u[i] = ra[(q0 + g * 4 + i) * 64u + c];
      acc[i] = 0.f;
    }
    for (int chunk = 0; chunk < 8; ++chunk) {
      unsigned base = (unsigned)(l0 + chunk * 64) * 64u;
      for (int it = 0; it < 4; ++it) {
        int i4 = it * TPB + tid;
        int row = i4 >> 4, c4 = (i4 & 15) * 4;
        *(float4*)&sm[row * 64 + c4] = *(const float4*)(pa + base + row * 64 + c4);
      }
      __syncthreads();
#pragma unroll 4
      for (int ll = 0; ll < 64; ++ll) {
        float x = sm[ll * 64 + c];
#pragma unroll
        for (int i = 0; i < 4; ++i) acc[i] += fmaxf(u[i] + x, 0.f);
      }
      __syncthreads();
    }
#pragma unroll
    for (int i = 0; i < 4; ++i)
      ws[OFF_SRP + (unsigned)(ls * 512 + q0 + g * 4 + i) * 64u + c] = acc[i];
  } else {
    int b = bid - 256;
    int l0 = b * 16;
    for (int it = 0; it < 16; ++it) {            // WaT[j][c'] = Wa[c'][j]
      int idx = it * TPB + tid;
      int a = idx >> 6, bb = idx & 63;
      sm[5120 + bb * 65 + a] = Wa[idx];
    }
    float v[4], acc[4];
#pragma unroll
    for (int i = 0; i < 4; ++i) {
      v[i] = pa[(unsigned)(l0 + g * 4 + i) * 64u + c];
      acc[i] = 0.f;
    }
    for (int chunk = 0; chunk < 8; ++chunk) {
      unsigned base = (unsigned)(chunk * 64) * 64u;
      for (int it = 0; it < 4; ++it) {
        int i4 = it * TPB + tid;
        int row = i4 >> 4, c4 = (i4 & 15) * 4;
        *(float4*)&sm[row * 64 + c4] = *(const float4*)(ra + base + row * 64 + c4);
      }
      __syncthreads();
#pragma unroll 4
      for (int qq = 0; qq < 64; ++qq) {
        float x = sm[qq * 64 + c];
#pragma unroll
        for (int i = 0; i < 4; ++i) acc[i] += fmaxf(v[i] + x, 0.f);
      }
      __syncthreads();
    }
#pragma unroll
    for (int i = 0; i < 4; ++i) sm[4096 + (g * 4 + i) * 64 + c] = acc[i];
    __syncthreads();
    // fused p_gate + val + partial max over this block's 16 l-rows
    float vmax = 0.f;   // vals are >= 0 (k>=0, gate>0)
    float bac = ba[c];
#pragma unroll
    for (int i = 0; i < 4; ++i) {
      int ll = g * 4 + i;
      float dot = 0.f;
#pragma unroll 8
      for (int jj = 0; jj < 64; ++jj)
        dot += sm[4096 + ll * 64 + jj] * sm[5120 + jj * 65 + c];
      float pg = 1.f / (1.f + __expf(-(dot * (1.f / 512.f) + bac)));
      float val = ws[OFF_K + (unsigned)(l0 + ll) * 64u + c] * (1.f + pg);
      vmax = fmaxf(vmax, val);
    }
    sm[9280 + g * 64 + c] = vmax;
    __syncthreads();
    if (tid < 64) {
      float m = fmaxf(fmaxf(sm[9280 + tid], sm[9280 + 64 + tid]),
                      fmaxf(sm[9280 + 128 + tid], sm[9280 + 192 + tid]));
      ws[OFF_PMAX + (unsigned)b * 64u + tid] = m;
    }
  }
}

// ============================================================================
// K4: final stage, 128 blocks x 4 q-rows. Key algebra: ctx's prot-half
// contributes a q-independent c1[n] = sum_j prot[j]*Wf1[n][64+j] to h1.
// Wf1/Wf2 read pre-transposed (lane-coalesced).
// ============================================================================
__global__ __launch_bounds__(TPB) void k4_final(
    const float* __restrict__ Wa,  const float* __restrict__ ba,
    const float* __restrict__ bf1, const float* __restrict__ bf2,
    const float* __restrict__ Wf3, const float* __restrict__ bf3,
    const float* __restrict__ ws,  float* __restrict__ out)
{
  __shared__ float wa[64 * 65];
  __shared__ float mr[256];
  __shared__ float pm[256];
  __shared__ float prot[64];
  __shared__ float rx[256];
  __shared__ float h1s[4 * 256];
  __shared__ float h2s[4 * 128];
  int bid = blockIdx.x, tid = threadIdx.x;
  int q0 = bid * 4;
  int q = tid >> 6, c = tid & 63;

  for (int it = 0; it < 16; ++it) {              // stage Wa [64][65]
    int idx = it * TPB + tid;
    wa[(idx >> 6) * 65 + (idx & 63)] = Wa[idx];
  }
  {                                              // Mr row (mean over L)
    float s = 0.f;
#pragma unroll
    for (int ls = 0; ls < 8; ++ls)
      s += ws[OFF_SRP + (unsigned)(ls * 512 + q0 + q) * 64u + c];
    mr[q * 64 + c] = s * (1.f / 4096.f);
  }
  {                                              // prot partial max
    float m = 0.f;
    for (int i = 0; i < 64; ++i)
      m = fmaxf(m, ws[OFF_PMAX + (unsigned)(q * 64 + i) * 64u + c]);
    pm[q * 64 + c] = m;
  }
  __syncthreads();
  if (tid < 64)
    prot[tid] = fmaxf(fmaxf(pm[tid], pm[64 + tid]),
                      fmaxf(pm[128 + tid], pm[192 + tid]));
  __syncthreads();
  {                                              // r_gate -> rxnfp
    float dot = 0.f;
#pragma unroll 8
    for (int j = 0; j < 64; ++j)
      dot += mr[q * 64 + j] * wa[c * 65 + j];
    float g = 1.f / (1.f + __expf(-(dot + ba[c])));
    rx[q * 64 + c] = ws[OFF_R + (unsigned)(q0 + q) * 64u + c] * (1.f + g);
  }
  __syncthreads();
  {                                              // h1 for 4 q; n = tid
    int n = tid;
    const float* wf1t = ws + OFF_WF1T;
    float a0 = 0, a1 = 0, a2 = 0, a3 = 0, c1 = 0;
#pragma unroll 4
    for (int j = 0; j < 64; ++j) {
      float w1 = wf1t[j * 256 + n];
      float w2 = wf1t[(64 + j) * 256 + n];
      c1 += prot[j] * w2;
      a0 += rx[j] * w1;
      a1 += rx[64 + j] * w1;
      a2 += rx[128 + j] * w1;
      a3 += rx[192 + j] * w1;
    }
    float bb = bf1[n] + c1;
    float v;
    v = a0 + bb; h1s[0 * 256 + n] = v > 0.f ? v : 0.01f * v;
    v = a1 + bb; h1s[1 * 256 + n] = v > 0.f ? v : 0.01f * v;
    v = a2 + bb; h1s[2 * 256 + n] = v > 0.f ? v : 0.01f * v;
    v = a3 + bb; h1s[3 * 256 + n] = v > 0.f ? v : 0.01f * v;
  }
  __syncthreads();
  {                                              // h2: m = tid&127, 2 q each
    int m = tid & 127, qh = tid >> 7;
    const float* wf2t = ws + OFF_WF2T;
    const float* h1a = h1s + (qh * 2) * 256;
    const float* h1b = h1s + (qh * 2 + 1) * 256;
    float b0 = 0, b1 = 0;
#pragma unroll 4
    for (int j = 0; j < 256; ++j) {
      float w = wf2t[j * 128 + m];
      b0 += h1a[j] * w;
      b1 += h1b[j] * w;
    }
    float bb = bf2[m];
    float v0 = b0 + bb, v1 = b1 + bb;
    h2s[(qh * 2) * 128 + m]     = v0 > 0.f ? v0 : 0.01f * v0;
    h2s[(qh * 2 + 1) * 128 + m] = v1 > 0.f ? v1 : 0.01f * v1;
  }
  __syncthreads();
  {                                              // out: wave = one q
    float v = h2s[q * 128 + c] * Wf3[c] + h2s[q * 128 + 64 + c] * Wf3[64 + c];
#pragma unroll
    for (int off = 32; off > 0; off >>= 1) v += __shfl_down(v, off);
    if (c == 0) out[q0 + q] = v + bf3[0];
  }
}

// ============================================================================
extern "C" void kernel_launch(void* const* d_in, const int* in_sizes, int n_in,
                              void* d_out, int out_size, void* d_ws, size_t ws_size,
                              hipStream_t stream)
{
  const float* reactions = (const float*)d_in[0];
  const float* protein   = (const float*)d_in[1];
  const float* Wc  = (const float*)d_in[2];
  const float* bc  = (const float*)d_in[3];
  const float* W1  = (const float*)d_in[4];
  const float* b1  = (const float*)d_in[5];
  const float* W2  = (const float*)d_in[6];
  const float* b2  = (const float*)d_in[7];
  const float* Wa  = (const float*)d_in[8];
  const float* ba  = (const float*)d_in[9];
  const float* Wpa = (const float*)d_in[10];
  const float* bpa = (const float*)d_in[11];
  const float* Wra = (const float*)d_in[12];
  const float* bra = (const float*)d_in[13];
  const float* Wf1 = (const float*)d_in[14];
  const float* bf1 = (const float*)d_in[15];
  const float* Wf2 = (const float*)d_in[16];
  const float* bf2 = (const float*)d_in[17];
  const float* Wf3 = (const float*)d_in[18];
  const float* bf3 = (const float*)d_in[19];
  float* ws  = (float*)d_ws;
  float* out = (float*)d_out;

  hipLaunchKernelGGL(k1_gemm, dim3(262), dim3(TPB), 0, stream,
                     protein, Wc, bc, W1, W2, Wf1, Wf2, ws);
  hipLaunchKernelGGL(k2_heads, dim3(144), dim3(TPB), 0, stream,
                     reactions, b1, b2, Wpa, bpa, Wra, bra, ws);
  hipLaunchKernelGGL(k3_interact, dim3(512), dim3(TPB), 0, stream,
                     Wa, ba, ws);
  hipLaunchKernelGGL(k4_final, dim3(128), dim3(TPB), 0, stream,
                     Wa, ba, bf1, bf2, Wf3, bf3, ws, out);
}

// Round 3
// 205.322 us; speedup vs baseline: 1.5844x; 1.1264x over previous
//
#include <hip/hip_runtime.h>
#include <math.h>

#define TPB 256

typedef __attribute__((ext_vector_type(8))) short s16x8;
typedef __attribute__((ext_vector_type(4))) float f32x4;

// ---------------- workspace layout (float offsets) ----------------
constexpr unsigned OFF_P    = 0u;                     // p    [4096][256] (relu'd)
constexpr unsigned OFF_K    = OFF_P    + 4096u*256u;  // k    [4096][64]
constexpr unsigned OFF_PA   = OFF_K    + 4096u*64u;   // pa   [4096][64]
constexpr unsigned OFF_R    = OFF_PA   + 4096u*64u;   // r    [512][64]
constexpr unsigned OFF_RA   = OFF_R    + 512u*64u;    // ra   [512][64]
constexpr unsigned OFF_SRP  = OFF_RA   + 512u*64u;    // Sr partials [8][512][64]
constexpr unsigned OFF_PMAX = OFF_SRP  + 8u*512u*64u; // pmax partials [256][64]
constexpr unsigned OFF_W1T  = OFF_PMAX + 256u*64u;    // W1^T  [256][64]
constexpr unsigned OFF_W2T  = OFF_W1T  + 256u*64u;    // W2^T  [256][64]
constexpr unsigned OFF_WF1T = OFF_W2T  + 256u*64u;    // Wf1^T [128][256]
constexpr unsigned OFF_WF2T = OFF_WF1T + 128u*256u;   // Wf2^T [256][128]

// round-to-nearest-even fp32 -> bf16
__device__ __forceinline__ short f2bf(float x) {
  union { float f; unsigned u; } v; v.f = x;
  unsigned r = v.u + 0x7FFFu + ((v.u >> 16) & 1u);
  return (short)(r >> 16);
}

// ============================================================================
// K1: p = relu(protein @ Wc^T + bc)  via bf16 MFMA 16x16x32.
// 128 GEMM blocks: 64 M-tiles x 2 N-tiles, tile 64x128, BK=64 (16 chunks).
// fp32 global -> RNE bf16 in regs -> LDS [row][64+8] bf16 (16B pad).
// Wave tile 32x64 (2m x 4n frags). Global prefetch of chunk k+1 over MFMA k.
// Tail blocks 128..133 transpose W1,W2,Wf1,Wf2 into ws (fp32).
// ============================================================================
__global__ __launch_bounds__(TPB, 2) void k1_gemm(
    const float* __restrict__ prot, const float* __restrict__ Wc,
    const float* __restrict__ bc,   const float* __restrict__ W1,
    const float* __restrict__ W2,   const float* __restrict__ Wf1,
    const float* __restrict__ Wf2,  float* __restrict__ ws)
{
  int bid = blockIdx.x;
  int tid = threadIdx.x;
  if (bid >= 128) {
    int tb = bid - 128;
    if (tb < 2) {                       // W1T/W2T [256][64]
      const float* W = (tb == 0) ? W1 : W2;
      float* WT = ws + ((tb == 0) ? OFF_W1T : OFF_W2T);
      for (int it = 0; it < 64; ++it) {
        int idx = it * TPB + tid;
        WT[idx] = W[(idx & 63) * 256 + (idx >> 6)];
      }
    } else if (tb < 4) {                // Wf1T [128][256], halves
      int h = tb - 2;
      for (int it = 0; it < 64; ++it) {
        int idx = h * 16384 + it * TPB + tid;
        ws[OFF_WF1T + idx] = Wf1[(idx & 255) * 128 + (idx >> 8)];
      }
    } else {                            // Wf2T [256][128], halves
      int h = tb - 4;
      for (int it = 0; it < 64; ++it) {
        int idx = h * 16384 + it * TPB + tid;
        ws[OFF_WF2T + idx] = Wf2[(idx & 127) * 256 + (idx >> 7)];
      }
    }
    return;
  }

  __shared__ __align__(16) short Asm[64 * 72];    // [m][64+8] bf16
  __shared__ __align__(16) short Bsm[128 * 72];   // [n][64+8] bf16

  int m0 = (bid >> 1) * 64;
  int n0 = (bid & 1) * 128;
  int wave = tid >> 6, lane = tid & 63;
  int wm = (wave >> 1) * 32, wn = (wave & 1) * 64;   // wave tile origin
  int lm = lane & 15, quad = lane >> 4;

  // staging maps
  int arow = tid >> 2, aseg = (tid & 3) * 16;   // A: 64 rows x 4 x 16 floats
  int brow = tid >> 1, bseg = (tid & 1) * 32;   // B: 128 rows x 2 x 32 floats

  const float* Ag = prot + (size_t)(m0 + arow) * 1024 + aseg;
  const float* Bg = Wc   + (size_t)(n0 + brow) * 1024 + bseg;

  float4 a4[4], b4[8];
#pragma unroll
  for (int i = 0; i < 4; ++i) a4[i] = *(const float4*)(Ag + i * 4);
#pragma unroll
  for (int i = 0; i < 8; ++i) b4[i] = *(const float4*)(Bg + i * 4);

  f32x4 acc[2][4] = {};

  for (int kc = 0; kc < 16; ++kc) {
    __syncthreads();                    // previous chunk's frag reads done
    // convert + store A (16 floats -> 2 x short8)
    {
      s16x8 s0, s1;
      s0[0]=f2bf(a4[0].x); s0[1]=f2bf(a4[0].y); s0[2]=f2bf(a4[0].z); s0[3]=f2bf(a4[0].w);
      s0[4]=f2bf(a4[1].x); s0[5]=f2bf(a4[1].y); s0[6]=f2bf(a4[1].z); s0[7]=f2bf(a4[1].w);
      s1[0]=f2bf(a4[2].x); s1[1]=f2bf(a4[2].y); s1[2]=f2bf(a4[2].z); s1[3]=f2bf(a4[2].w);
      s1[4]=f2bf(a4[3].x); s1[5]=f2bf(a4[3].y); s1[6]=f2bf(a4[3].z); s1[7]=f2bf(a4[3].w);
      *(s16x8*)&Asm[arow * 72 + aseg]     = s0;
      *(s16x8*)&Asm[arow * 72 + aseg + 8] = s1;
    }
    // convert + store B (32 floats -> 4 x short8)
#pragma unroll
    for (int h = 0; h < 4; ++h) {
      s16x8 s;
      s[0]=f2bf(b4[h*2].x);   s[1]=f2bf(b4[h*2].y);
      s[2]=f2bf(b4[h*2].z);   s[3]=f2bf(b4[h*2].w);
      s[4]=f2bf(b4[h*2+1].x); s[5]=f2bf(b4[h*2+1].y);
      s[6]=f2bf(b4[h*2+1].z); s[7]=f2bf(b4[h*2+1].w);
      *(s16x8*)&Bsm[brow * 72 + bseg + h * 8] = s;
    }
    // prefetch next chunk while this one computes
    if (kc < 15) {
#pragma unroll
      for (int i = 0; i < 4; ++i) a4[i] = *(const float4*)(Ag + (kc + 1) * 64 + i * 4);
#pragma unroll
      for (int i = 0; i < 8; ++i) b4[i] = *(const float4*)(Bg + (kc + 1) * 64 + i * 4);
    }
    __syncthreads();
#pragma unroll
    for (int ks = 0; ks < 2; ++ks) {
      s16x8 af[2], bfv[4];
#pragma unroll
      for (int mi = 0; mi < 2; ++mi)
        af[mi] = *(const s16x8*)&Asm[(wm + mi * 16 + lm) * 72 + ks * 32 + quad * 8];
#pragma unroll
      for (int ni = 0; ni < 4; ++ni)
        bfv[ni] = *(const s16x8*)&Bsm[(wn + ni * 16 + lm) * 72 + ks * 32 + quad * 8];
#pragma unroll
      for (int mi = 0; mi < 2; ++mi)
#pragma unroll
        for (int ni = 0; ni < 4; ++ni)
          acc[mi][ni] = __builtin_amdgcn_mfma_f32_16x16x32_bf16(
              af[mi], bfv[ni], acc[mi][ni], 0, 0, 0);
    }
  }

  // epilogue: C/D layout col=lane&15, row=quad*4+reg (m89-verified)
#pragma unroll
  for (int ni = 0; ni < 4; ++ni) {
    int col = n0 + wn + ni * 16 + lm;
    float bcv = bc[col];
#pragma unroll
    for (int mi = 0; mi < 2; ++mi) {
#pragma unroll
      for (int r = 0; r < 4; ++r) {
        int row = m0 + wm + mi * 16 + quad * 4 + r;
        ws[OFF_P + (unsigned)row * 256u + col] = fmaxf(acc[mi][ni][r] + bcv, 0.f);
      }
    }
  }
}

// ============================================================================
// K2: two heads, 16-row tiles (288 blocks):
//   bid<256 : k  = relu(p @ W1^T + b1);  pa = k @ Wpa^T + bpa
//   bid>=256: r  = relu(react @ W2^T+b2); ra = r @ Wra^T + bra
// ============================================================================
__global__ __launch_bounds__(TPB) void k2_heads(
    const float* __restrict__ reactions,
    const float* __restrict__ b1,  const float* __restrict__ b2,
    const float* __restrict__ Wpa, const float* __restrict__ bpa,
    const float* __restrict__ Wra, const float* __restrict__ bra,
    float* __restrict__ ws)
{
  __shared__ float ps[16 * 256];   // src tile 16 KB
  __shared__ float ks_[16 * 65];   // stage-1 out (padded)
  __shared__ float wst[64 * 65];   // stage-2 weight^T (padded)
  int bid = blockIdx.x, tid = threadIdx.x;
  bool isProt = bid < 256;
  int row0 = (isProt ? bid : (bid - 256)) * 16;
  const float* src  = isProt ? (ws + OFF_P) : reactions;
  const float* WTg  = ws + (isProt ? OFF_W1T : OFF_W2T);
  const float* bv   = isProt ? b1 : b2;
  const float* W2nd = isProt ? Wpa : Wra;
  const float* b2nd = isProt ? bpa : bra;
  float* out1 = ws + (isProt ? OFF_K : OFF_R);
  float* out2 = ws + (isProt ? OFF_PA : OFF_RA);

#pragma unroll
  for (int it = 0; it < 4; ++it) {               // stage src [16][256]
    int i4 = it * TPB + tid;
    int row = i4 >> 6, c4 = (i4 & 63) * 4;
    *(float4*)&ps[row * 256 + c4] =
        *(const float4*)(src + (row0 + row) * 256u + c4);
  }
#pragma unroll
  for (int it = 0; it < 16; ++it) {              // wst[j][j2] = W2nd[j2][j]
    int idx = it * TPB + tid;
    int a = idx >> 6, b = idx & 63;
    wst[b * 65 + a] = W2nd[idx];
  }
  __syncthreads();

  int j = tid & 63, g = tid >> 6;                // 4 rows per thread
  float acc[4];
  float bb = bv[j];
#pragma unroll
  for (int i = 0; i < 4; ++i) acc[i] = bb;
#pragma unroll 8
  for (int cc = 0; cc < 256; ++cc) {
    float w = WTg[cc * 64 + j];                  // coalesced (L2)
#pragma unroll
    for (int i = 0; i < 4; ++i)
      acc[i] += ps[(g * 4 + i) * 256 + cc] * w;  // LDS broadcast
  }
#pragma unroll
  for (int i = 0; i < 4; ++i) {
    float kv = fmaxf(acc[i], 0.f);
    int row = g * 4 + i;
    out1[(row0 + row) * 64u + j] = kv;
    ks_[row * 65 + j] = kv;
  }
  __syncthreads();

  float bb2 = b2nd[j];
  float acc2[4];
#pragma unroll
  for (int i = 0; i < 4; ++i) acc2[i] = bb2;
#pragma unroll 8
  for (int jj = 0; jj < 64; ++jj) {
    float w = wst[jj * 65 + j];
#pragma unroll
    for (int i = 0; i < 4; ++i)
      acc2[i] += ks_[(g * 4 + i) * 65 + jj] * w;
  }
#pragma unroll
  for (int i = 0; i < 4; ++i)
    out2[(row0 + g * 4 + i) * 64u + j] = acc2[i];
}

// ============================================================================
// K3: interaction sums. 512 blocks:
//   bid<256 : Sr partials: block=(q-tile of 16, L-slice of 512)
//   bid>=256: Sp (full q sum) for l-tile of 16 + FUSED p_gate + k*(1+g) + max
// ============================================================================
__global__ __launch_bounds__(TPB) void k3_interact(
    const float* __restrict__ Wa, const float* __restrict__ ba,
    float* __restrict__ ws)
{
  // sm layout: [0,4096) tile; [4096,5120) sp; [5120,9280) WaT 64x65; [9280,9536) red
  __shared__ float sm[9536];
  int bid = blockIdx.x, tid = threadIdx.x;
  int c = tid & 63, g = tid >> 6;
  const float* ra = ws + OFF_RA;
  const float* pa = ws + OFF_PA;

  if (bid < 256) {
    int qt = bid >> 3, ls = bid & 7;
    int q0 = qt * 16, l0 = ls * 512;
    float u[4], acc[4];
#pragma unroll
    for (int i = 0; i < 4; ++i) {
      u[i] = ra[(q0 + g * 4 + i) * 64u + c];
      acc[i] = 0.f;
    }
    for (int chunk = 0; chunk < 8; ++chunk) {
      unsigned base = (unsigned)(l0 + chunk * 64) * 64u;
      for (int it = 0; it < 4; ++it) {
        int i4 = it * TPB + tid;
        int row = i4 >> 4, c4 = (i4 & 15) * 4;
        *(float4*)&sm[row * 64 + c4] = *(const float4*)(pa + base + row * 64 + c4);
      }
      __syncthreads();
#pragma unroll 4
      for (int ll = 0; ll < 64; ++ll) {
        float x = sm[ll * 64 + c];
#pragma unroll
        for (int i = 0; i < 4; ++i) acc[i] += fmaxf(u[i] + x, 0.f);
      }
      __syncthreads();
    }
#pragma unroll
    for (int i = 0; i < 4; ++i)
      ws[OFF_SRP + (unsigned)(ls * 512 + q0 + g * 4 + i) * 64u + c] = acc[i];
  } else {
    int b = bid - 256;
    int l0 = b * 16;
    for (int it = 0; it < 16; ++it) {            // WaT[j][c'] = Wa[c'][j]
      int idx = it * TPB + tid;
      int a = idx >> 6, bb = idx & 63;
      sm[5120 + bb * 65 + a] = Wa[idx];
    }
    float v[4], acc[4];
#pragma unroll
    for (int i = 0; i < 4; ++i) {
      v[i] = pa[(unsigned)(l0 + g * 4 + i) * 64u + c];
      acc[i] = 0.f;
    }
    for (int chunk = 0; chunk < 8; ++chunk) {
      unsigned base = (unsigned)(chunk * 64) * 64u;
      for (int it = 0; it < 4; ++it) {
        int i4 = it * TPB + tid;
        int row = i4 >> 4, c4 = (i4 & 15) * 4;
        *(float4*)&sm[row * 64 + c4] = *(const float4*)(ra + base + row * 64 + c4);
      }
      __syncthreads();
#pragma unroll 4
      for (int qq = 0; qq < 64; ++qq) {
        float x = sm[qq * 64 + c];
#pragma unroll
        for (int i = 0; i < 4; ++i) acc[i] += fmaxf(v[i] + x, 0.f);
      }
      __syncthreads();
    }
#pragma unroll
    for (int i = 0; i < 4; ++i) sm[4096 + (g * 4 + i) * 64 + c] = acc[i];
    __syncthreads();
    // fused p_gate + val + partial max over this block's 16 l-rows
    float vmax = 0.f;   // vals are >= 0 (k>=0, gate>0)
    float bac = ba[c];
#pragma unroll
    for (int i = 0; i < 4; ++i) {
      int ll = g * 4 + i;
      float dot = 0.f;
#pragma unroll 8
      for (int jj = 0; jj < 64; ++jj)
        dot += sm[4096 + ll * 64 + jj] * sm[5120 + jj * 65 + c];
      float pg = 1.f / (1.f + __expf(-(dot * (1.f / 512.f) + bac)));
      float val = ws[OFF_K + (unsigned)(l0 + ll) * 64u + c] * (1.f + pg);
      vmax = fmaxf(vmax, val);
    }
    sm[9280 + g * 64 + c] = vmax;
    __syncthreads();
    if (tid < 64) {
      float m = fmaxf(fmaxf(sm[9280 + tid], sm[9280 + 64 + tid]),
                      fmaxf(sm[9280 + 128 + tid], sm[9280 + 192 + tid]));
      ws[OFF_PMAX + (unsigned)b * 64u + tid] = m;
    }
  }
}

// ============================================================================
// K4: final stage, 128 blocks x 4 q-rows. ctx's prot-half contributes a
// q-independent c1[n]; Wf1/Wf2 read pre-transposed (lane-coalesced).
// ============================================================================
__global__ __launch_bounds__(TPB) void k4_final(
    const float* __restrict__ Wa,  const float* __restrict__ ba,
    const float* __restrict__ bf1, const float* __restrict__ bf2,
    const float* __restrict__ Wf3, const float* __restrict__ bf3,
    const float* __restrict__ ws,  float* __restrict__ out)
{
  __shared__ float wa[64 * 65];
  __shared__ float mr[256];
  __shared__ float pm[256];
  __shared__ float prot[64];
  __shared__ float rx[256];
  __shared__ float h1s[4 * 256];
  __shared__ float h2s[4 * 128];
  int bid = blockIdx.x, tid = threadIdx.x;
  int q0 = bid * 4;
  int q = tid >> 6, c = tid & 63;

  for (int it = 0; it < 16; ++it) {              // stage Wa [64][65]
    int idx = it * TPB + tid;
    wa[(idx >> 6) * 65 + (idx & 63)] = Wa[idx];
  }
  {                                              // Mr row (mean over L)
    float s = 0.f;
#pragma unroll
    for (int ls = 0; ls < 8; ++ls)
      s += ws[OFF_SRP + (unsigned)(ls * 512 + q0 + q) * 64u + c];
    mr[q * 64 + c] = s * (1.f / 4096.f);
  }
  {                                              // prot partial max
    float m = 0.f;
    for (int i = 0; i < 64; ++i)
      m = fmaxf(m, ws[OFF_PMAX + (unsigned)(q * 64 + i) * 64u + c]);
    pm[q * 64 + c] = m;
  }
  __syncthreads();
  if (tid < 64)
    prot[tid] = fmaxf(fmaxf(pm[tid], pm[64 + tid]),
                      fmaxf(pm[128 + tid], pm[192 + tid]));
  __syncthreads();
  {                                              // r_gate -> rxnfp
    float dot = 0.f;
#pragma unroll 8
    for (int j = 0; j < 64; ++j)
      dot += mr[q * 64 + j] * wa[c * 65 + j];
    float g = 1.f / (1.f + __expf(-(dot + ba[c])));
    rx[q * 64 + c] = ws[OFF_R + (unsigned)(q0 + q) * 64u + c] * (1.f + g);
  }
  __syncthreads();
  {                                              // h1 for 4 q; n = tid
    int n = tid;
    const float* wf1t = ws + OFF_WF1T;
    float a0 = 0, a1 = 0, a2 = 0, a3 = 0, c1 = 0;
#pragma unroll 4
    for (int j = 0; j < 64; ++j) {
      float w1 = wf1t[j * 256 + n];
      float w2 = wf1t[(64 + j) * 256 + n];
      c1 += prot[j] * w2;
      a0 += rx[j] * w1;
      a1 += rx[64 + j] * w1;
      a2 += rx[128 + j] * w1;
      a3 += rx[192 + j] * w1;
    }
    float bb = bf1[n] + c1;
    float v;
    v = a0 + bb; h1s[0 * 256 + n] = v > 0.f ? v : 0.01f * v;
    v = a1 + bb; h1s[1 * 256 + n] = v > 0.f ? v : 0.01f * v;
    v = a2 + bb; h1s[2 * 256 + n] = v > 0.f ? v : 0.01f * v;
    v = a3 + bb; h1s[3 * 256 + n] = v > 0.f ? v : 0.01f * v;
  }
  __syncthreads();
  {                                              // h2: m = tid&127, 2 q each
    int m = tid & 127, qh = tid >> 7;
    const float* wf2t = ws + OFF_WF2T;
    const float* h1a = h1s + (qh * 2) * 256;
    const float* h1b = h1s + (qh * 2 + 1) * 256;
    float b0 = 0, b1 = 0;
#pragma unroll 4
    for (int j = 0; j < 256; ++j) {
      float w = wf2t[j * 128 + m];
      b0 += h1a[j] * w;
      b1 += h1b[j] * w;
    }
    float bb = bf2[m];
    float v0 = b0 + bb, v1 = b1 + bb;
    h2s[(qh * 2) * 128 + m]     = v0 > 0.f ? v0 : 0.01f * v0;
    h2s[(qh * 2 + 1) * 128 + m] = v1 > 0.f ? v1 : 0.01f * v1;
  }
  __syncthreads();
  {                                              // out: wave = one q
    float v = h2s[q * 128 + c] * Wf3[c] + h2s[q * 128 + 64 + c] * Wf3[64 + c];
#pragma unroll
    for (int off = 32; off > 0; off >>= 1) v += __shfl_down(v, off);
    if (c == 0) out[q0 + q] = v + bf3[0];
  }
}

// ============================================================================
extern "C" void kernel_launch(void* const* d_in, const int* in_sizes, int n_in,
                              void* d_out, int out_size, void* d_ws, size_t ws_size,
                              hipStream_t stream)
{
  const float* reactions = (const float*)d_in[0];
  const float* protein   = (const float*)d_in[1];
  const float* Wc  = (const float*)d_in[2];
  const float* bc  = (const float*)d_in[3];
  const float* W1  = (const float*)d_in[4];
  const float* b1  = (const float*)d_in[5];
  const float* W2  = (const float*)d_in[6];
  const float* b2  = (const float*)d_in[7];
  const float* Wa  = (const float*)d_in[8];
  const float* ba  = (const float*)d_in[9];
  const float* Wpa = (const float*)d_in[10];
  const float* bpa = (const float*)d_in[11];
  const float* Wra = (const float*)d_in[12];
  const float* bra = (const float*)d_in[13];
  const float* Wf1 = (const float*)d_in[14];
  const float* bf1 = (const float*)d_in[15];
  const float* Wf2 = (const float*)d_in[16];
  const float* bf2 = (const float*)d_in[17];
  const float* Wf3 = (const float*)d_in[18];
  const float* bf3 = (const float*)d_in[19];
  float* ws  = (float*)d_ws;
  float* out = (float*)d_out;

  hipLaunchKernelGGL(k1_gemm, dim3(134), dim3(TPB), 0, stream,
                     protein, Wc, bc, W1, W2, Wf1, Wf2, ws);
  hipLaunchKernelGGL(k2_heads, dim3(288), dim3(TPB), 0, stream,
                     reactions, b1, b2, Wpa, bpa, Wra, bra, ws);
  hipLaunchKernelGGL(k3_interact, dim3(512), dim3(TPB), 0, stream,
                     Wa, ba, ws);
  hipLaunchKernelGGL(k4_final, dim3(128), dim3(TPB), 0, stream,
                     Wa, ba, bf1, bf2, Wf3, bf3, ws, out);
}

// Round 4
// 190.294 us; speedup vs baseline: 1.7095x; 1.0790x over previous
//
#include <hip/hip_runtime.h>
#include <hip/hip_bf16.h>
#include <math.h>

#define TPB 256

typedef __attribute__((ext_vector_type(8))) short s16x8;
typedef __attribute__((ext_vector_type(4))) float f32x4;

// ---------------- workspace layout (float offsets) ----------------
constexpr unsigned OFF_P    = 0u;                     // p    [4096][256] (relu'd)
constexpr unsigned OFF_K    = OFF_P    + 4096u*256u;  // k    [4096][64]
constexpr unsigned OFF_PA   = OFF_K    + 4096u*64u;   // pa   [4096][64]
constexpr unsigned OFF_R    = OFF_PA   + 4096u*64u;   // r    [512][64]
constexpr unsigned OFF_RA   = OFF_R    + 512u*64u;    // ra   [512][64]
constexpr unsigned OFF_SRP  = OFF_RA   + 512u*64u;    // Sr partials [8][512][64]
constexpr unsigned OFF_PMAX = OFF_SRP  + 8u*512u*64u; // pmax partials [256][64]
constexpr unsigned OFF_W1T  = OFF_PMAX + 256u*64u;    // (unused)
constexpr unsigned OFF_W2T  = OFF_W1T  + 256u*64u;    // (unused)
constexpr unsigned OFF_WF1T = OFF_W2T  + 256u*64u;    // Wf1^T [128][256]
constexpr unsigned OFF_WF2T = OFF_WF1T + 128u*256u;   // Wf2^T [256][128]

// scalar RNE fp32 -> bf16
__device__ __forceinline__ short f2bf(float x) {
  union { float f; unsigned u; } v; v.f = x;
  unsigned r = v.u + 0x7FFFu + ((v.u >> 16) & 1u);
  return (short)(r >> 16);
}
// packed RNE: 2 floats -> 2 bf16 in one dword (v_cvt_pk_bf16_f32 on gfx950)
__device__ __forceinline__ unsigned pkbf(float a, float b) {
  __hip_bfloat162 h = __float22bfloat162_rn(make_float2(a, b));
  union { __hip_bfloat162 h2; unsigned u; } v; v.h2 = h;
  return v.u;
}
union U8 { s16x8 s; unsigned u[4]; };

// ============================================================================
// K1: p = relu(protein @ Wc^T + bc)  via bf16 MFMA 16x16x32.
// 128 GEMM blocks: 64 M-tiles x 2 N-tiles, tile 64x128, BK=64 (16 chunks).
// fp32 global -> packed RNE bf16 in regs -> LDS [row][64+8] bf16.
// Wave tile 32x64 (2m x 4n frags). Global prefetch of chunk k+1 over MFMA k.
// Tail blocks 128..135: LDS-tiled COALESCED transposes of Wf1/Wf2 (the old
// uncoalesced versions straggled ~10+ us past the GEMM blocks).
// ============================================================================
__global__ __launch_bounds__(TPB, 2) void k1_gemm(
    const float* __restrict__ prot, const float* __restrict__ Wc,
    const float* __restrict__ bc,   const float* __restrict__ Wf1,
    const float* __restrict__ Wf2,  float* __restrict__ ws)
{
  int bid = blockIdx.x;
  int tid = threadIdx.x;
  if (bid >= 128) {
    // 8 blocks x 8 tiles of 32x32 LDS transpose. 64 tiles:
    //   t<32 : Wf1 [256][128] -> WF1T [128][256]
    //   t>=32: Wf2 [128][256] -> WF2T [256][128]
    __shared__ float tl[32 * 33];
    int tb = bid - 128;
    for (int i = 0; i < 8; ++i) {
      int t = tb * 8 + i;
      const float* S; float* D; int snc, dnc, sr, sc;
      if (t < 32) {
        S = Wf1; D = ws + OFF_WF1T; snc = 128; dnc = 256;
        sr = (t >> 2) * 32; sc = (t & 3) * 32;
      } else {
        int t2 = t - 32;
        S = Wf2; D = ws + OFF_WF2T; snc = 256; dnc = 128;
        sr = (t2 >> 3) * 32; sc = (t2 & 7) * 32;
      }
#pragma unroll
      for (int it = 0; it < 4; ++it) {
        int idx = it * TPB + tid;
        int r = idx >> 5, c = idx & 31;
        tl[c * 33 + r] = S[(size_t)(sr + r) * snc + sc + c];   // coalesced read
      }
      __syncthreads();
#pragma unroll
      for (int it = 0; it < 4; ++it) {
        int idx = it * TPB + tid;
        int r = idx >> 5, c = idx & 31;
        D[(size_t)(sc + r) * dnc + sr + c] = tl[r * 33 + c];   // coalesced write
      }
      __syncthreads();
    }
    return;
  }

  __shared__ __align__(16) short Asm[64 * 72];    // [m][64+8] bf16
  __shared__ __align__(16) short Bsm[128 * 72];   // [n][64+8] bf16

  int m0 = (bid >> 1) * 64;
  int n0 = (bid & 1) * 128;
  int wave = tid >> 6, lane = tid & 63;
  int wm = (wave >> 1) * 32, wn = (wave & 1) * 64;   // wave tile origin
  int lm = lane & 15, quad = lane >> 4;

  // staging maps
  int arow = tid >> 2, aseg = (tid & 3) * 16;   // A: 64 rows x 4 x 16 floats
  int brow = tid >> 1, bseg = (tid & 1) * 32;   // B: 128 rows x 2 x 32 floats

  const float* Ag = prot + (size_t)(m0 + arow) * 1024 + aseg;
  const float* Bg = Wc   + (size_t)(n0 + brow) * 1024 + bseg;

  float4 a4[4], b4[8];
#pragma unroll
  for (int i = 0; i < 4; ++i) a4[i] = *(const float4*)(Ag + i * 4);
#pragma unroll
  for (int i = 0; i < 8; ++i) b4[i] = *(const float4*)(Bg + i * 4);

  f32x4 acc[2][4] = {};

  for (int kc = 0; kc < 16; ++kc) {
    __syncthreads();                    // previous chunk's frag reads done
    {
      U8 s0, s1;
      s0.u[0] = pkbf(a4[0].x, a4[0].y); s0.u[1] = pkbf(a4[0].z, a4[0].w);
      s0.u[2] = pkbf(a4[1].x, a4[1].y); s0.u[3] = pkbf(a4[1].z, a4[1].w);
      s1.u[0] = pkbf(a4[2].x, a4[2].y); s1.u[1] = pkbf(a4[2].z, a4[2].w);
      s1.u[2] = pkbf(a4[3].x, a4[3].y); s1.u[3] = pkbf(a4[3].z, a4[3].w);
      *(s16x8*)&Asm[arow * 72 + aseg]     = s0.s;
      *(s16x8*)&Asm[arow * 72 + aseg + 8] = s1.s;
    }
#pragma unroll
    for (int h = 0; h < 4; ++h) {
      U8 s;
      s.u[0] = pkbf(b4[h*2].x,   b4[h*2].y);
      s.u[1] = pkbf(b4[h*2].z,   b4[h*2].w);
      s.u[2] = pkbf(b4[h*2+1].x, b4[h*2+1].y);
      s.u[3] = pkbf(b4[h*2+1].z, b4[h*2+1].w);
      *(s16x8*)&Bsm[brow * 72 + bseg + h * 8] = s.s;
    }
    if (kc < 15) {                      // prefetch next chunk over this MFMA
#pragma unroll
      for (int i = 0; i < 4; ++i) a4[i] = *(const float4*)(Ag + (kc + 1) * 64 + i * 4);
#pragma unroll
      for (int i = 0; i < 8; ++i) b4[i] = *(const float4*)(Bg + (kc + 1) * 64 + i * 4);
    }
    __syncthreads();
#pragma unroll
    for (int ks = 0; ks < 2; ++ks) {
      s16x8 af[2], bfv[4];
#pragma unroll
      for (int mi = 0; mi < 2; ++mi)
        af[mi] = *(const s16x8*)&Asm[(wm + mi * 16 + lm) * 72 + ks * 32 + quad * 8];
#pragma unroll
      for (int ni = 0; ni < 4; ++ni)
        bfv[ni] = *(const s16x8*)&Bsm[(wn + ni * 16 + lm) * 72 + ks * 32 + quad * 8];
#pragma unroll
      for (int mi = 0; mi < 2; ++mi)
#pragma unroll
        for (int ni = 0; ni < 4; ++ni)
          acc[mi][ni] = __builtin_amdgcn_mfma_f32_16x16x32_bf16(
              af[mi], bfv[ni], acc[mi][ni], 0, 0, 0);
    }
  }

  // epilogue: C/D layout col=lane&15, row=quad*4+reg
#pragma unroll
  for (int ni = 0; ni < 4; ++ni) {
    int col = n0 + wn + ni * 16 + lm;
    float bcv = bc[col];
#pragma unroll
    for (int mi = 0; mi < 2; ++mi) {
#pragma unroll
      for (int r = 0; r < 4; ++r) {
        int row = m0 + wm + mi * 16 + quad * 4 + r;
        ws[OFF_P + (unsigned)row * 256u + col] = fmaxf(acc[mi][ni][r] + bcv, 0.f);
      }
    }
  }
}

// ============================================================================
// K2: two heads via bf16 MFMA, 144 blocks x 32 rows, both stages fused:
//   bid<128 : k  = relu(p @ W1^T + b1);  pa = k @ Wpa^T + bpa
//   bid>=128: r  = relu(react @ W2^T+b2); ra = r @ Wra^T + bra
// Weights read in NATIVE [n][k] layout (B-operand wants [n][k] - no transpose).
// Stage-1 k-tile round-trips LDS in bf16 A-layout for stage-2 (flash-P style).
// ============================================================================
__global__ __launch_bounds__(TPB, 2) void k2_heads(
    const float* __restrict__ reactions,
    const float* __restrict__ W1,  const float* __restrict__ b1,
    const float* __restrict__ W2,  const float* __restrict__ b2,
    const float* __restrict__ Wpa, const float* __restrict__ bpa,
    const float* __restrict__ Wra, const float* __restrict__ bra,
    float* __restrict__ ws)
{
  __shared__ __align__(16) short Asm[32 * 264];   // src rows [32][256+8]
  __shared__ __align__(16) short Bsm[64 * 264];   // W1/W2 [64][256+8]
  __shared__ __align__(16) short Ksm[32 * 72];    // k-tile bf16 [32][64+8]
  __shared__ __align__(16) short Wsm[64 * 72];    // Wpa/Wra [64][64+8]
  int bid = blockIdx.x, tid = threadIdx.x;
  bool isProt = bid < 128;
  int row0 = (isProt ? bid : (bid - 128)) * 32;
  const float* src  = isProt ? (ws + OFF_P) : reactions;
  const float* Wst1 = isProt ? W1 : W2;
  const float* bv   = isProt ? b1 : b2;
  const float* Wst2 = isProt ? Wpa : Wra;
  const float* b2nd = isProt ? bpa : bra;
  float* out1 = ws + (isProt ? OFF_K : OFF_R);
  float* out2 = ws + (isProt ? OFF_PA : OFF_RA);

  {                                     // stage A [32][256] fp32 -> bf16
    int row = tid >> 3, seg = (tid & 7) * 32;
    const float* sp = src + (size_t)(row0 + row) * 256 + seg;
    float4 f[8];
#pragma unroll
    for (int i = 0; i < 8; ++i) f[i] = *(const float4*)(sp + i * 4);
#pragma unroll
    for (int i = 0; i < 4; ++i) {
      U8 s;
      s.u[0] = pkbf(f[2*i].x,   f[2*i].y);
      s.u[1] = pkbf(f[2*i].z,   f[2*i].w);
      s.u[2] = pkbf(f[2*i+1].x, f[2*i+1].y);
      s.u[3] = pkbf(f[2*i+1].z, f[2*i+1].w);
      *(s16x8*)&Asm[row * 264 + seg + i * 8] = s.s;
    }
  }
  {                                     // stage B = W1/W2 [64][256] native
    int row = tid >> 2, seg = (tid & 3) * 64;
    const float* sp = Wst1 + (size_t)row * 256 + seg;
#pragma unroll
    for (int i = 0; i < 8; ++i) {
      float4 fa = *(const float4*)(sp + i * 8);
      float4 fb = *(const float4*)(sp + i * 8 + 4);
      U8 s;
      s.u[0] = pkbf(fa.x, fa.y); s.u[1] = pkbf(fa.z, fa.w);
      s.u[2] = pkbf(fb.x, fb.y); s.u[3] = pkbf(fb.z, fb.w);
      *(s16x8*)&Bsm[row * 264 + seg + i * 8] = s.s;
    }
  }
  {                                     // stage Wpa/Wra [64][64] native
    int row = tid >> 2, seg = (tid & 3) * 16;
    const float* sp = Wst2 + (size_t)row * 64 + seg;
#pragma unroll
    for (int i = 0; i < 2; ++i) {
      float4 fa = *(const float4*)(sp + i * 8);
      float4 fb = *(const float4*)(sp + i * 8 + 4);
      U8 s;
      s.u[0] = pkbf(fa.x, fa.y); s.u[1] = pkbf(fa.z, fa.w);
      s.u[2] = pkbf(fb.x, fb.y); s.u[3] = pkbf(fb.z, fb.w);
      *(s16x8*)&Wsm[row * 72 + seg + i * 8] = s.s;
    }
  }
  __syncthreads();

  int wave = tid >> 6, lane = tid & 63;
  int lm = lane & 15, quad = lane >> 4;
  int wm = (wave >> 1) * 16, wn = (wave & 1) * 32;   // wave tile 16x32

  f32x4 acc[2] = {};
#pragma unroll
  for (int kc = 0; kc < 8; ++kc) {
    s16x8 a = *(const s16x8*)&Asm[(wm + lm) * 264 + kc * 32 + quad * 8];
#pragma unroll
    for (int ni = 0; ni < 2; ++ni) {
      s16x8 b = *(const s16x8*)&Bsm[(wn + ni * 16 + lm) * 264 + kc * 32 + quad * 8];
      acc[ni] = __builtin_amdgcn_mfma_f32_16x16x32_bf16(a, b, acc[ni], 0, 0, 0);
    }
  }
  // epilogue 1: k = relu(acc + b); fp32 -> ws, bf16 -> Ksm (A-layout)
#pragma unroll
  for (int ni = 0; ni < 2; ++ni) {
    int col = wn + ni * 16 + lm;
    float bb = bv[col];
#pragma unroll
    for (int r = 0; r < 4; ++r) {
      int row = wm + quad * 4 + r;
      float kv = fmaxf(acc[ni][r] + bb, 0.f);
      out1[(size_t)(row0 + row) * 64 + col] = kv;
      Ksm[row * 72 + col] = f2bf(kv);
    }
  }
  __syncthreads();

  f32x4 acc2[2] = {};
#pragma unroll
  for (int kc = 0; kc < 2; ++kc) {
    s16x8 a = *(const s16x8*)&Ksm[(wm + lm) * 72 + kc * 32 + quad * 8];
#pragma unroll
    for (int ni = 0; ni < 2; ++ni) {
      s16x8 b = *(const s16x8*)&Wsm[(wn + ni * 16 + lm) * 72 + kc * 32 + quad * 8];
      acc2[ni] = __builtin_amdgcn_mfma_f32_16x16x32_bf16(a, b, acc2[ni], 0, 0, 0);
    }
  }
#pragma unroll
  for (int ni = 0; ni < 2; ++ni) {
    int col = wn + ni * 16 + lm;
    float bb = b2nd[col];
#pragma unroll
    for (int r = 0; r < 4; ++r) {
      int row = wm + quad * 4 + r;
      out2[(size_t)(row0 + row) * 64 + col] = acc2[ni][r] + bb;
    }
  }
}

// ============================================================================
// K3: interaction sums. 512 blocks:
//   bid<256 : Sr partials: block=(q-tile of 16, L-slice of 512)
//   bid>=256: Sp (full q sum) for l-tile of 16 + FUSED p_gate + k*(1+g) + max
// ============================================================================
__global__ __launch_bounds__(TPB) void k3_interact(
    const float* __restrict__ Wa, const float* __restrict__ ba,
    float* __restrict__ ws)
{
  // sm layout: [0,4096) tile; [4096,5120) sp; [5120,9280) WaT 64x65; [9280,9536) red
  __shared__ float sm[9536];
  int bid = blockIdx.x, tid = threadIdx.x;
  int c = tid & 63, g = tid >> 6;
  const float* ra = ws + OFF_RA;
  const float* pa = ws + OFF_PA;

  if (bid < 256) {
    int qt = bid >> 3, ls = bid & 7;
    int q0 = qt * 16, l0 = ls * 512;
    float u[4], acc[4];
#pragma unroll
    for (int i = 0; i < 4; ++i) {
      u[i] = ra[(q0 + g * 4 + i) * 64u + c];
      acc[i] = 0.f;
    }
    for (int chunk = 0; chunk < 8; ++chunk) {
      unsigned base = (unsigned)(l0 + chunk * 64) * 64u;
      for (int it = 0; it < 4; ++it) {
        int i4 = it * TPB + tid;
        int row = i4 >> 4, c4 = (i4 & 15) * 4;
        *(float4*)&sm[row * 64 + c4] = *(const float4*)(pa + base + row * 64 + c4);
      }
      __syncthreads();
#pragma unroll 4
      for (int ll = 0; ll < 64; ++ll) {
        float x = sm[ll * 64 + c];
#pragma unroll
        for (int i = 0; i < 4; ++i) acc[i] += fmaxf(u[i] + x, 0.f);
      }
      __syncthreads();
    }
#pragma unroll
    for (int i = 0; i < 4; ++i)
      ws[OFF_SRP + (unsigned)(ls * 512 + q0 + g * 4 + i) * 64u + c] = acc[i];
  } else {
    int b = bid - 256;
    int l0 = b * 16;
    for (int it = 0; it < 16; ++it) {            // WaT[j][c'] = Wa[c'][j]
      int idx = it * TPB + tid;
      int a = idx >> 6, bb = idx & 63;
      sm[5120 + bb * 65 + a] = Wa[idx];
    }
    float v[4], acc[4];
#pragma unroll
    for (int i = 0; i < 4; ++i) {
      v[i] = pa[(unsigned)(l0 + g * 4 + i) * 64u + c];
      acc[i] = 0.f;
    }
    for (int chunk = 0; chunk < 8; ++chunk) {
      unsigned base = (unsigned)(chunk * 64) * 64u;
      for (int it = 0; it < 4; ++it) {
        int i4 = it * TPB + tid;
        int row = i4 >> 4, c4 = (i4 & 15) * 4;
        *(float4*)&sm[row * 64 + c4] = *(const float4*)(ra + base + row * 64 + c4);
      }
      __syncthreads();
#pragma unroll 4
      for (int qq = 0; qq < 64; ++qq) {
        float x = sm[qq * 64 + c];
#pragma unroll
        for (int i = 0; i < 4; ++i) acc[i] += fmaxf(v[i] + x, 0.f);
      }
      __syncthreads();
    }
#pragma unroll
    for (int i = 0; i < 4; ++i) sm[4096 + (g * 4 + i) * 64 + c] = acc[i];
    __syncthreads();
    // fused p_gate + val + partial max over this block's 16 l-rows
    float vmax = 0.f;   // vals are >= 0 (k>=0, gate>0)
    float bac = ba[c];
#pragma unroll
    for (int i = 0; i < 4; ++i) {
      int ll = g * 4 + i;
      float dot = 0.f;
#pragma unroll 8
      for (int jj = 0; jj < 64; ++jj)
        dot += sm[4096 + ll * 64 + jj] * sm[5120 + jj * 65 + c];
      float pg = 1.f / (1.f + __expf(-(dot * (1.f / 512.f) + bac)));
      float val = ws[OFF_K + (unsigned)(l0 + ll) * 64u + c] * (1.f + pg);
      vmax = fmaxf(vmax, val);
    }
    sm[9280 + g * 64 + c] = vmax;
    __syncthreads();
    if (tid < 64) {
      float m = fmaxf(fmaxf(sm[9280 + tid], sm[9280 + 64 + tid]),
                      fmaxf(sm[9280 + 128 + tid], sm[9280 + 192 + tid]));
      ws[OFF_PMAX + (unsigned)b * 64u + tid] = m;
    }
  }
}

// ============================================================================
// K4: final stage, 256 blocks x 2 q-rows (2x parallelism vs last round's 128;
// it's latency-bound on serial load chains).
// ============================================================================
__global__ __launch_bounds__(TPB) void k4_final(
    const float* __restrict__ Wa,  const float* __restrict__ ba,
    const float* __restrict__ bf1, const float* __restrict__ bf2,
    const float* __restrict__ Wf3, const float* __restrict__ bf3,
    const float* __restrict__ ws,  float* __restrict__ out)
{
  __shared__ float wa[64 * 65];
  __shared__ float mr[128];
  __shared__ float pm[256];
  __shared__ float prot[64];
  __shared__ float rx[128];
  __shared__ float h1s[2 * 256];
  __shared__ float h2s[2 * 128];
  __shared__ float red[8];
  int bid = blockIdx.x, tid = threadIdx.x;
  int q0 = bid * 2;

  for (int it = 0; it < 16; ++it) {              // stage Wa [64][65]
    int idx = it * TPB + tid;
    wa[(idx >> 6) * 65 + (idx & 63)] = Wa[idx];
  }
  if (tid < 128) {                               // Mr rows (mean over L)
    int q = tid >> 6, c = tid & 63;
    float s = 0.f;
#pragma unroll
    for (int ls = 0; ls < 8; ++ls)
      s += ws[OFF_SRP + (unsigned)(ls * 512 + q0 + q) * 64u + c];
    mr[tid] = s * (1.f / 4096.f);
  }
  {                                              // prot partial max
    int c = tid & 63, ch = tid >> 6;
    float m = 0.f;
#pragma unroll 8
    for (int i = 0; i < 64; ++i)
      m = fmaxf(m, ws[OFF_PMAX + (unsigned)(ch * 64 + i) * 64u + c]);
    pm[ch * 64 + c] = m;
  }
  __syncthreads();
  if (tid < 64)
    prot[tid] = fmaxf(fmaxf(pm[tid], pm[64 + tid]),
                      fmaxf(pm[128 + tid], pm[192 + tid]));
  __syncthreads();
  if (tid < 128) {                               // r_gate -> rxnfp
    int q = tid >> 6, c = tid & 63;
    float dot = 0.f;
#pragma unroll 8
    for (int j = 0; j < 64; ++j)
      dot += mr[q * 64 + j] * wa[c * 65 + j];
    float g = 1.f / (1.f + __expf(-(dot + ba[c])));
    rx[tid] = ws[OFF_R + (unsigned)(q0 + q) * 64u + c] * (1.f + g);
  }
  __syncthreads();
  {                                              // h1 for 2 q; n = tid
    int n = tid;
    const float* wf1t = ws + OFF_WF1T;
    float a0 = 0, a1 = 0, c1 = 0;
#pragma unroll 8
    for (int j = 0; j < 64; ++j) {
      float w1 = wf1t[j * 256 + n];
      float w2 = wf1t[(64 + j) * 256 + n];
      c1 += prot[j] * w2;
      a0 += rx[j] * w1;
      a1 += rx[64 + j] * w1;
    }
    float bb = bf1[n] + c1;
    float v;
    v = a0 + bb; h1s[n]       = v > 0.f ? v : 0.01f * v;
    v = a1 + bb; h1s[256 + n] = v > 0.f ? v : 0.01f * v;
  }
  __syncthreads();
  {                                              // h2: m = tid&127, 1 q each
    int m = tid & 127, qh = tid >> 7;
    const float* wf2t = ws + OFF_WF2T;
    const float* h1a = h1s + qh * 256;
    float b0 = 0;
#pragma unroll 8
    for (int j = 0; j < 256; ++j)
      b0 += h1a[j] * wf2t[j * 128 + m];
    float v = b0 + bf2[m];
    h2s[qh * 128 + m] = v > 0.f ? v : 0.01f * v;
  }
  __syncthreads();
  {                                              // out: wave w -> q=w>>1, half=w&1
    int wave = tid >> 6, lane = tid & 63;
    int q = wave >> 1, h = wave & 1;
    float v = h2s[q * 128 + h * 64 + lane] * Wf3[h * 64 + lane];
#pragma unroll
    for (int off = 32; off > 0; off >>= 1) v += __shfl_down(v, off);
    if (lane == 0) red[wave] = v;
  }
  __syncthreads();
  if (tid < 2) out[q0 + tid] = red[tid * 2] + red[tid * 2 + 1] + bf3[0];
}

// ============================================================================
extern "C" void kernel_launch(void* const* d_in, const int* in_sizes, int n_in,
                              void* d_out, int out_size, void* d_ws, size_t ws_size,
                              hipStream_t stream)
{
  const float* reactions = (const float*)d_in[0];
  const float* protein   = (const float*)d_in[1];
  const float* Wc  = (const float*)d_in[2];
  const float* bc  = (const float*)d_in[3];
  const float* W1  = (const float*)d_in[4];
  const float* b1  = (const float*)d_in[5];
  const float* W2  = (const float*)d_in[6];
  const float* b2  = (const float*)d_in[7];
  const float* Wa  = (const float*)d_in[8];
  const float* ba  = (const float*)d_in[9];
  const float* Wpa = (const float*)d_in[10];
  const float* bpa = (const float*)d_in[11];
  const float* Wra = (const float*)d_in[12];
  const float* bra = (const float*)d_in[13];
  const float* Wf1 = (const float*)d_in[14];
  const float* bf1 = (const float*)d_in[15];
  const float* Wf2 = (const float*)d_in[16];
  const float* bf2 = (const float*)d_in[17];
  const float* Wf3 = (const float*)d_in[18];
  const float* bf3 = (const float*)d_in[19];
  float* ws  = (float*)d_ws;
  float* out = (float*)d_out;

  hipLaunchKernelGGL(k1_gemm, dim3(136), dim3(TPB), 0, stream,
                     protein, Wc, bc, Wf1, Wf2, ws);
  hipLaunchKernelGGL(k2_heads, dim3(144), dim3(TPB), 0, stream,
                     reactions, W1, b1, W2, b2, Wpa, bpa, Wra, bra, ws);
  hipLaunchKernelGGL(k3_interact, dim3(512), dim3(TPB), 0, stream,
                     Wa, ba, ws);
  hipLaunchKernelGGL(k4_final, dim3(256), dim3(TPB), 0, stream,
                     Wa, ba, bf1, bf2, Wf3, bf3, ws, out);
}

// Round 5
// 178.827 us; speedup vs baseline: 1.8191x; 1.0641x over previous
//
#include <hip/hip_runtime.h>
#include <hip/hip_bf16.h>
#include <math.h>

#define TPB 256

typedef __attribute__((ext_vector_type(8))) short s16x8;
typedef __attribute__((ext_vector_type(4))) float f32x4;

#define MFMA16(a, b, c) __builtin_amdgcn_mfma_f32_16x16x32_bf16((a), (b), (c), 0, 0, 0)

// ---------------- workspace layout (float offsets) ----------------
constexpr unsigned OFF_P    = 0u;                     // p    [4096][256] (relu'd)
constexpr unsigned OFF_K    = OFF_P    + 4096u*256u;  // k    [4096][64]
constexpr unsigned OFF_PA   = OFF_K    + 4096u*64u;   // pa   [4096][64]
constexpr unsigned OFF_R    = OFF_PA   + 4096u*64u;   // r    [512][64]
constexpr unsigned OFF_RA   = OFF_R    + 512u*64u;    // ra   [512][64]
constexpr unsigned OFF_SR   = OFF_RA   + 512u*64u;    // SR   [512][64] (atomicAdd, zeroed by k1 tails)
constexpr unsigned OFF_PMAX = OFF_SR   + 512u*64u;    // PMAX [64]      (atomicMax fp32-bits, zeroed)

// scalar RNE fp32 -> bf16
__device__ __forceinline__ short f2bf(float x) {
  union { float f; unsigned u; } v; v.f = x;
  unsigned r = v.u + 0x7FFFu + ((v.u >> 16) & 1u);
  return (short)(r >> 16);
}
// packed RNE: 2 floats -> 2 bf16 in one dword
__device__ __forceinline__ unsigned pkbf(float a, float b) {
  __hip_bfloat162 h = __float22bfloat162_rn(make_float2(a, b));
  union { __hip_bfloat162 h2; unsigned u; } v; v.h2 = h;
  return v.u;
}
union U8 { s16x8 s; unsigned u[4]; };

// ============================================================================
// K1: p = relu(protein @ Wc^T + bc)  via bf16 MFMA 16x16x32.
// 512 GEMM blocks (tile 32x64: 128 M-tiles x 4 N-tiles) -> 2 blocks/CU so
// barrier drains overlap across blocks (R4's 128-block version left half the
// CUs idle at 1 wave/SIMD). BK=64, 16 chunks, prefetch chunk k+1 over MFMA k.
// A/B re-reads (x4 / x128) are L2/L3-absorbed (R2 FETCH evidence: 34 MB).
// Tail blocks 512,513: zero SR [512][64] + PMAX [64] for k3's atomics.
// ============================================================================
__global__ __launch_bounds__(TPB, 2) void k1_gemm(
    const float* __restrict__ prot, const float* __restrict__ Wc,
    const float* __restrict__ bc,   float* __restrict__ ws)
{
  int bid = blockIdx.x;
  int tid = threadIdx.x;
  if (bid >= 512) {
    int tb = bid - 512;
    unsigned base = OFF_SR + (unsigned)tb * 16384u;
#pragma unroll
    for (int it = 0; it < 16; ++it) {
      int idx = it * TPB + tid;
      *(float4*)&ws[base + (unsigned)idx * 4u] = make_float4(0.f, 0.f, 0.f, 0.f);
    }
    if (tb == 1 && tid < 16)
      *(float4*)&ws[OFF_PMAX + tid * 4] = make_float4(0.f, 0.f, 0.f, 0.f);
    return;
  }

  __shared__ __align__(16) short Asm[32 * 72];    // [m][64+8] bf16
  __shared__ __align__(16) short Bsm[64 * 72];    // [n][64+8] bf16

  int m0 = (bid >> 2) * 32;
  int n0 = (bid & 3) * 64;
  int wave = tid >> 6, lane = tid & 63;
  int wm = (wave & 1) * 16, wn = (wave >> 1) * 32;   // wave tile 16x32
  int lm = lane & 15, quad = lane >> 4;

  int arow = tid >> 3, aseg = (tid & 7) * 8;    // A: 32 rows x 8 x 8 floats
  int brow = tid >> 2, bseg = (tid & 3) * 16;   // B: 64 rows x 4 x 16 floats

  const float* Ag = prot + (size_t)(m0 + arow) * 1024 + aseg;
  const float* Bg = Wc   + (size_t)(n0 + brow) * 1024 + bseg;

  float4 a4[2], b4[4];
#pragma unroll
  for (int i = 0; i < 2; ++i) a4[i] = *(const float4*)(Ag + i * 4);
#pragma unroll
  for (int i = 0; i < 4; ++i) b4[i] = *(const float4*)(Bg + i * 4);

  f32x4 acc[2] = {};

  for (int kc = 0; kc < 16; ++kc) {
    __syncthreads();                    // previous chunk's frag reads done
    {
      U8 s;
      s.u[0] = pkbf(a4[0].x, a4[0].y); s.u[1] = pkbf(a4[0].z, a4[0].w);
      s.u[2] = pkbf(a4[1].x, a4[1].y); s.u[3] = pkbf(a4[1].z, a4[1].w);
      *(s16x8*)&Asm[arow * 72 + aseg] = s.s;
    }
#pragma unroll
    for (int h = 0; h < 2; ++h) {
      U8 s;
      s.u[0] = pkbf(b4[h*2].x,   b4[h*2].y);
      s.u[1] = pkbf(b4[h*2].z,   b4[h*2].w);
      s.u[2] = pkbf(b4[h*2+1].x, b4[h*2+1].y);
      s.u[3] = pkbf(b4[h*2+1].z, b4[h*2+1].w);
      *(s16x8*)&Bsm[brow * 72 + bseg + h * 8] = s.s;
    }
    if (kc < 15) {                      // prefetch next chunk over this MFMA
#pragma unroll
      for (int i = 0; i < 2; ++i) a4[i] = *(const float4*)(Ag + (kc + 1) * 64 + i * 4);
#pragma unroll
      for (int i = 0; i < 4; ++i) b4[i] = *(const float4*)(Bg + (kc + 1) * 64 + i * 4);
    }
    __syncthreads();
#pragma unroll
    for (int ks = 0; ks < 2; ++ks) {
      s16x8 af = *(const s16x8*)&Asm[(wm + lm) * 72 + ks * 32 + quad * 8];
#pragma unroll
      for (int ni = 0; ni < 2; ++ni) {
        s16x8 bfv = *(const s16x8*)&Bsm[(wn + ni * 16 + lm) * 72 + ks * 32 + quad * 8];
        acc[ni] = MFMA16(af, bfv, acc[ni]);
      }
    }
  }

  // epilogue: C/D layout col=lane&15, row=quad*4+reg
#pragma unroll
  for (int ni = 0; ni < 2; ++ni) {
    int col = n0 + wn + ni * 16 + lm;
    float bcv = bc[col];
#pragma unroll
    for (int r = 0; r < 4; ++r) {
      int row = m0 + wm + quad * 4 + r;
      ws[OFF_P + (unsigned)row * 256u + col] = fmaxf(acc[ni][r] + bcv, 0.f);
    }
  }
}

// ============================================================================
// K2: two heads via bf16 MFMA, 144 blocks x 32 rows, both stages fused:
//   bid<128 : k  = relu(p @ W1^T + b1);  pa = k @ Wpa^T + bpa
//   bid>=128: r  = relu(react @ W2^T+b2); ra = r @ Wra^T + bra
// Weights read in NATIVE [n][k] layout (B-operand wants [n][k] - no transpose).
// ============================================================================
__global__ __launch_bounds__(TPB, 2) void k2_heads(
    const float* __restrict__ reactions,
    const float* __restrict__ W1,  const float* __restrict__ b1,
    const float* __restrict__ W2,  const float* __restrict__ b2,
    const float* __restrict__ Wpa, const float* __restrict__ bpa,
    const float* __restrict__ Wra, const float* __restrict__ bra,
    float* __restrict__ ws)
{
  __shared__ __align__(16) short Asm[32 * 264];   // src rows [32][256+8]
  __shared__ __align__(16) short Bsm[64 * 264];   // W1/W2 [64][256+8]
  __shared__ __align__(16) short Ksm[32 * 72];    // k-tile bf16 [32][64+8]
  __shared__ __align__(16) short Wsm[64 * 72];    // Wpa/Wra [64][64+8]
  int bid = blockIdx.x, tid = threadIdx.x;
  bool isProt = bid < 128;
  int row0 = (isProt ? bid : (bid - 128)) * 32;
  const float* src  = isProt ? (ws + OFF_P) : reactions;
  const float* Wst1 = isProt ? W1 : W2;
  const float* bv   = isProt ? b1 : b2;
  const float* Wst2 = isProt ? Wpa : Wra;
  const float* b2nd = isProt ? bpa : bra;
  float* out1 = ws + (isProt ? OFF_K : OFF_R);
  float* out2 = ws + (isProt ? OFF_PA : OFF_RA);

  {                                     // stage A [32][256] fp32 -> bf16
    int row = tid >> 3, seg = (tid & 7) * 32;
    const float* sp = src + (size_t)(row0 + row) * 256 + seg;
    float4 f[8];
#pragma unroll
    for (int i = 0; i < 8; ++i) f[i] = *(const float4*)(sp + i * 4);
#pragma unroll
    for (int i = 0; i < 4; ++i) {
      U8 s;
      s.u[0] = pkbf(f[2*i].x,   f[2*i].y);
      s.u[1] = pkbf(f[2*i].z,   f[2*i].w);
      s.u[2] = pkbf(f[2*i+1].x, f[2*i+1].y);
      s.u[3] = pkbf(f[2*i+1].z, f[2*i+1].w);
      *(s16x8*)&Asm[row * 264 + seg + i * 8] = s.s;
    }
  }
  {                                     // stage B = W1/W2 [64][256] native
    int row = tid >> 2, seg = (tid & 3) * 64;
    const float* sp = Wst1 + (size_t)row * 256 + seg;
#pragma unroll
    for (int i = 0; i < 8; ++i) {
      float4 fa = *(const float4*)(sp + i * 8);
      float4 fb = *(const float4*)(sp + i * 8 + 4);
      U8 s;
      s.u[0] = pkbf(fa.x, fa.y); s.u[1] = pkbf(fa.z, fa.w);
      s.u[2] = pkbf(fb.x, fb.y); s.u[3] = pkbf(fb.z, fb.w);
      *(s16x8*)&Bsm[row * 264 + seg + i * 8] = s.s;
    }
  }
  {                                     // stage Wpa/Wra [64][64] native
    int row = tid >> 2, seg = (tid & 3) * 16;
    const float* sp = Wst2 + (size_t)row * 64 + seg;
#pragma unroll
    for (int i = 0; i < 2; ++i) {
      float4 fa = *(const float4*)(sp + i * 8);
      float4 fb = *(const float4*)(sp + i * 8 + 4);
      U8 s;
      s.u[0] = pkbf(fa.x, fa.y); s.u[1] = pkbf(fa.z, fa.w);
      s.u[2] = pkbf(fb.x, fb.y); s.u[3] = pkbf(fb.z, fb.w);
      *(s16x8*)&Wsm[row * 72 + seg + i * 8] = s.s;
    }
  }
  __syncthreads();

  int wave = tid >> 6, lane = tid & 63;
  int lm = lane & 15, quad = lane >> 4;
  int wm = (wave >> 1) * 16, wn = (wave & 1) * 32;   // wave tile 16x32

  f32x4 acc[2] = {};
#pragma unroll
  for (int kc = 0; kc < 8; ++kc) {
    s16x8 a = *(const s16x8*)&Asm[(wm + lm) * 264 + kc * 32 + quad * 8];
#pragma unroll
    for (int ni = 0; ni < 2; ++ni) {
      s16x8 b = *(const s16x8*)&Bsm[(wn + ni * 16 + lm) * 264 + kc * 32 + quad * 8];
      acc[ni] = MFMA16(a, b, acc[ni]);
    }
  }
  // epilogue 1: k = relu(acc + b); fp32 -> ws, bf16 -> Ksm (A-layout)
#pragma unroll
  for (int ni = 0; ni < 2; ++ni) {
    int col = wn + ni * 16 + lm;
    float bb = bv[col];
#pragma unroll
    for (int r = 0; r < 4; ++r) {
      int row = wm + quad * 4 + r;
      float kv = fmaxf(acc[ni][r] + bb, 0.f);
      out1[(size_t)(row0 + row) * 64 + col] = kv;
      Ksm[row * 72 + col] = f2bf(kv);
    }
  }
  __syncthreads();

  f32x4 acc2[2] = {};
#pragma unroll
  for (int kc = 0; kc < 2; ++kc) {
    s16x8 a = *(const s16x8*)&Ksm[(wm + lm) * 72 + kc * 32 + quad * 8];
#pragma unroll
    for (int ni = 0; ni < 2; ++ni) {
      s16x8 b = *(const s16x8*)&Wsm[(wn + ni * 16 + lm) * 72 + kc * 32 + quad * 8];
      acc2[ni] = MFMA16(a, b, acc2[ni]);
    }
  }
#pragma unroll
  for (int ni = 0; ni < 2; ++ni) {
    int col = wn + ni * 16 + lm;
    float bb = b2nd[col];
#pragma unroll
    for (int r = 0; r < 4; ++r) {
      int row = wm + quad * 4 + r;
      out2[(size_t)(row0 + row) * 64 + col] = acc2[ni][r] + bb;
    }
  }
}

// ============================================================================
// K3: interaction sums. 512 blocks:
//   bid<256 : Sr partials -> atomicAdd into SR[512][64] (zeroed by k1 tails)
//   bid>=256: Sp (full q sum) + FUSED p_gate + k*(1+g) + atomicMax PMAX[64]
// (atomicMax int-bits is order-correct: all vals >= 0, PMAX zero-initialized)
// ============================================================================
__global__ __launch_bounds__(TPB) void k3_interact(
    const float* __restrict__ Wa, const float* __restrict__ ba,
    float* __restrict__ ws)
{
  // sm layout: [0,4096) tile; [4096,5120) sp; [5120,9280) WaT 64x65
  __shared__ float sm[9280];
  int bid = blockIdx.x, tid = threadIdx.x;
  int c = tid & 63, g = tid >> 6;
  const float* ra = ws + OFF_RA;
  const float* pa = ws + OFF_PA;

  if (bid < 256) {
    int qt = bid >> 3, ls = bid & 7;
    int q0 = qt * 16, l0 = ls * 512;
    float u[4], acc[4];
#pragma unroll
    for (int i = 0; i < 4; ++i) {
      u[i] = ra[(q0 + g * 4 + i) * 64u + c];
      acc[i] = 0.f;
    }
    for (int chunk = 0; chunk < 8; ++chunk) {
      unsigned base = (unsigned)(l0 + chunk * 64) * 64u;
      for (int it = 0; it < 4; ++it) {
        int i4 = it * TPB + tid;
        int row = i4 >> 4, c4 = (i4 & 15) * 4;
        *(float4*)&sm[row * 64 + c4] = *(const float4*)(pa + base + row * 64 + c4);
      }
      __syncthreads();
#pragma unroll 4
      for (int ll = 0; ll < 64; ++ll) {
        float x = sm[ll * 64 + c];
#pragma unroll
        for (int i = 0; i < 4; ++i) acc[i] += fmaxf(u[i] + x, 0.f);
      }
      __syncthreads();
    }
#pragma unroll
    for (int i = 0; i < 4; ++i)
      atomicAdd(&ws[OFF_SR + (unsigned)(q0 + g * 4 + i) * 64u + c], acc[i]);
  } else {
    int b = bid - 256;
    int l0 = b * 16;
    for (int it = 0; it < 16; ++it) {            // WaT[j][c'] = Wa[c'][j]
      int idx = it * TPB + tid;
      int a = idx >> 6, bb = idx & 63;
      sm[5120 + bb * 65 + a] = Wa[idx];
    }
    float v[4], acc[4];
#pragma unroll
    for (int i = 0; i < 4; ++i) {
      v[i] = pa[(unsigned)(l0 + g * 4 + i) * 64u + c];
      acc[i] = 0.f;
    }
    for (int chunk = 0; chunk < 8; ++chunk) {
      unsigned base = (unsigned)(chunk * 64) * 64u;
      for (int it = 0; it < 4; ++it) {
        int i4 = it * TPB + tid;
        int row = i4 >> 4, c4 = (i4 & 15) * 4;
        *(float4*)&sm[row * 64 + c4] = *(const float4*)(ra + base + row * 64 + c4);
      }
      __syncthreads();
#pragma unroll 4
      for (int qq = 0; qq < 64; ++qq) {
        float x = sm[qq * 64 + c];
#pragma unroll
        for (int i = 0; i < 4; ++i) acc[i] += fmaxf(v[i] + x, 0.f);
      }
      __syncthreads();
    }
#pragma unroll
    for (int i = 0; i < 4; ++i) sm[4096 + (g * 4 + i) * 64 + c] = acc[i];
    __syncthreads();
    // fused p_gate + val + per-thread max over its 4 l-rows
    float vmax = 0.f;   // vals >= 0 (k>=0, gate>0)
    float bac = ba[c];
#pragma unroll
    for (int i = 0; i < 4; ++i) {
      int ll = g * 4 + i;
      float dot = 0.f;
#pragma unroll 8
      for (int jj = 0; jj < 64; ++jj)
        dot += sm[4096 + ll * 64 + jj] * sm[5120 + jj * 65 + c];
      float pg = 1.f / (1.f + __expf(-(dot * (1.f / 512.f) + bac)));
      float val = ws[OFF_K + (unsigned)(l0 + ll) * 64u + c] * (1.f + pg);
      vmax = fmaxf(vmax, val);
    }
    atomicMax((int*)&ws[OFF_PMAX + c], __float_as_int(vmax));
  }
}

// ============================================================================
// K4: merged final stage, 32 blocks x 16 q. All matmul-shaped pieces as MFMA:
//   gate = sigmoid(mr @ Wa[n][k]-native + ba)    (16x64, K=64)
//   h1   = leaky(ctx @ Wf1-native + bf1)         (16x256, K=128)
//   h2   = leaky(h1 @ Wf2-native + bf2)          (16x128, K=256)
//   out  = h2 @ Wf3 + bf3                        (cross-lane reduce)
// Weights staged to LDS bf16 with wide coalesced pipelined loads (no serial
// dependent-load chains -> cold-cache latency is pipelined, not exposed).
// ============================================================================
__global__ __launch_bounds__(TPB) void k4_final(
    const float* __restrict__ Wa,  const float* __restrict__ ba,
    const float* __restrict__ Wf1, const float* __restrict__ bf1,
    const float* __restrict__ Wf2, const float* __restrict__ bf2,
    const float* __restrict__ Wf3, const float* __restrict__ bf3,
    float* __restrict__ ws, float* __restrict__ out)
{
  __shared__ __align__(16) short mrb[16 * 72];     // mr bf16 (A for gate)
  __shared__ __align__(16) short wab[64 * 72];     // Wa bf16 (B for gate)
  __shared__ __align__(16) short ctxb[16 * 136];   // ctx bf16 (A for h1)
  __shared__ __align__(16) short h1b[16 * 264];    // h1 bf16 (A for h2)
  __shared__ __align__(16) short wgt[256 * 136];   // Wf1 [256][136] then Wf2 [128][264]
  __shared__ float red[64];
  int bid = blockIdx.x, tid = threadIdx.x;
  int q0 = bid * 16;
  int wave = tid >> 6, lane = tid & 63;
  int lm = lane & 15, quad = lane >> 4;

  {                                     // stage mr = SR/4096 -> bf16 [16][72]
    int q = tid >> 4, c4 = (tid & 15) * 4;
    float4 v = *(const float4*)&ws[OFF_SR + (unsigned)(q0 + q) * 64u + c4];
    uint2 st = make_uint2(pkbf(v.x * (1.f/4096.f), v.y * (1.f/4096.f)),
                          pkbf(v.z * (1.f/4096.f), v.w * (1.f/4096.f)));
    *(uint2*)&mrb[q * 72 + c4] = st;
  }
#pragma unroll
  for (int it = 0; it < 4; ++it) {      // stage Wa [64][64] -> bf16 [64][72]
    int i4 = it * TPB + tid;
    int row = i4 >> 4, c4 = (i4 & 15) * 4;
    float4 v = *(const float4*)&Wa[row * 64 + c4];
    uint2 st = make_uint2(pkbf(v.x, v.y), pkbf(v.z, v.w));
    *(uint2*)&wab[row * 72 + c4] = st;
  }
  __syncthreads();

  // gate MFMA: wave w -> c-tile [w*16, w*16+16)
  f32x4 gacc = {};
#pragma unroll
  for (int kc = 0; kc < 2; ++kc) {
    s16x8 a = *(const s16x8*)&mrb[lm * 72 + kc * 32 + quad * 8];
    s16x8 b = *(const s16x8*)&wab[(wave * 16 + lm) * 72 + kc * 32 + quad * 8];
    gacc = MFMA16(a, b, gacc);
  }
  {                                     // epilogue: rx + prot halves -> ctxb
    int c = wave * 16 + lm;
    float bac = ba[c];
    short pb = f2bf(ws[OFF_PMAX + c]);  // prot[c] (atomicMax result, fp32 bits)
#pragma unroll
    for (int r = 0; r < 4; ++r) {
      int q = quad * 4 + r;
      float gg = 1.f / (1.f + __expf(-(gacc[r] + bac)));
      float rv = ws[OFF_R + (unsigned)(q0 + q) * 64u + c];
      ctxb[q * 136 + c]      = f2bf(rv * (1.f + gg));
      ctxb[q * 136 + 64 + c] = pb;
    }
  }
#pragma unroll 4
  for (int it = 0; it < 32; ++it) {     // stage Wf1 [256][128] -> wgt [256][136]
    int i4 = it * TPB + tid;
    int row = i4 >> 5, c4 = (i4 & 31) * 4;
    float4 v = *(const float4*)&Wf1[row * 128 + c4];
    uint2 st = make_uint2(pkbf(v.x, v.y), pkbf(v.z, v.w));
    *(uint2*)&wgt[row * 136 + c4] = st;
  }
  __syncthreads();

  // h1 MFMA: wave w covers n in [w*64, w*64+64): 4 n-tiles x 4 k-chunks
  f32x4 h[4] = {};
#pragma unroll
  for (int kc = 0; kc < 4; ++kc) {
    s16x8 a = *(const s16x8*)&ctxb[lm * 136 + kc * 32 + quad * 8];
#pragma unroll
    for (int nt = 0; nt < 4; ++nt) {
      s16x8 b = *(const s16x8*)&wgt[(wave * 64 + nt * 16 + lm) * 136 + kc * 32 + quad * 8];
      h[nt] = MFMA16(a, b, h[nt]);
    }
  }
#pragma unroll
  for (int nt = 0; nt < 4; ++nt) {
    int n = wave * 64 + nt * 16 + lm;
    float bb = bf1[n];
#pragma unroll
    for (int r = 0; r < 4; ++r) {
      int q = quad * 4 + r;
      float v = h[nt][r] + bb;
      v = v > 0.f ? v : 0.01f * v;
      h1b[q * 264 + n] = f2bf(v);
    }
  }
  __syncthreads();                      // h1b complete; wgt reads done

#pragma unroll 4
  for (int it = 0; it < 32; ++it) {     // stage Wf2 [128][256] -> wgt [128][264]
    int i4 = it * TPB + tid;
    int row = i4 >> 6, c4 = (i4 & 63) * 4;
    float4 v = *(const float4*)&Wf2[row * 256 + c4];
    uint2 st = make_uint2(pkbf(v.x, v.y), pkbf(v.z, v.w));
    *(uint2*)&wgt[row * 264 + c4] = st;
  }
  __syncthreads();

  // h2 MFMA: wave w covers m in [w*32, w*32+32): 2 n-tiles x 8 k-chunks
  f32x4 o[2] = {};
#pragma unroll
  for (int kc = 0; kc < 8; ++kc) {
    s16x8 a = *(const s16x8*)&h1b[lm * 264 + kc * 32 + quad * 8];
#pragma unroll
    for (int nt = 0; nt < 2; ++nt) {
      s16x8 b = *(const s16x8*)&wgt[(wave * 32 + nt * 16 + lm) * 264 + kc * 32 + quad * 8];
      o[nt] = MFMA16(a, b, o[nt]);
    }
  }
  float pv[4] = {0.f, 0.f, 0.f, 0.f};
#pragma unroll
  for (int nt = 0; nt < 2; ++nt) {
    int m = wave * 32 + nt * 16 + lm;
    float bb = bf2[m], w3 = Wf3[m];
#pragma unroll
    for (int r = 0; r < 4; ++r) {
      float v = o[nt][r] + bb;
      v = v > 0.f ? v : 0.01f * v;
      pv[r] += v * w3;
    }
  }
#pragma unroll
  for (int msk = 1; msk < 16; msk <<= 1)
#pragma unroll
    for (int r = 0; r < 4; ++r) pv[r] += __shfl_xor(pv[r], msk);
  if (lm == 0) {
#pragma unroll
    for (int r = 0; r < 4; ++r) red[(quad * 4 + r) * 4 + wave] = pv[r];
  }
  __syncthreads();
  if (tid < 16)
    out[q0 + tid] = red[tid * 4] + red[tid * 4 + 1] + red[tid * 4 + 2] +
                    red[tid * 4 + 3] + bf3[0];
}

// ============================================================================
extern "C" void kernel_launch(void* const* d_in, const int* in_sizes, int n_in,
                              void* d_out, int out_size, void* d_ws, size_t ws_size,
                              hipStream_t stream)
{
  const float* reactions = (const float*)d_in[0];
  const float* protein   = (const float*)d_in[1];
  const float* Wc  = (const float*)d_in[2];
  const float* bc  = (const float*)d_in[3];
  const float* W1  = (const float*)d_in[4];
  const float* b1  = (const float*)d_in[5];
  const float* W2  = (const float*)d_in[6];
  const float* b2  = (const float*)d_in[7];
  const float* Wa  = (const float*)d_in[8];
  const float* ba  = (const float*)d_in[9];
  const float* Wpa = (const float*)d_in[10];
  const float* bpa = (const float*)d_in[11];
  const float* Wra = (const float*)d_in[12];
  const float* bra = (const float*)d_in[13];
  const float* Wf1 = (const float*)d_in[14];
  const float* bf1 = (const float*)d_in[15];
  const float* Wf2 = (const float*)d_in[16];
  const float* bf2 = (const float*)d_in[17];
  const float* Wf3 = (const float*)d_in[18];
  const float* bf3 = (const float*)d_in[19];
  float* ws  = (float*)d_ws;
  float* out = (float*)d_out;

  hipLaunchKernelGGL(k1_gemm, dim3(514), dim3(TPB), 0, stream,
                     protein, Wc, bc, ws);
  hipLaunchKernelGGL(k2_heads, dim3(144), dim3(TPB), 0, stream,
                     reactions, W1, b1, W2, b2, Wpa, bpa, Wra, bra, ws);
  hipLaunchKernelGGL(k3_interact, dim3(512), dim3(TPB), 0, stream,
                     Wa, ba, ws);
  hipLaunchKernelGGL(k4_final, dim3(32), dim3(TPB), 0, stream,
                     Wa, ba, Wf1, bf1, Wf2, bf2, Wf3, bf3, ws, out);
}